// Round 8
// baseline (2122.292 us; speedup 1.0000x reference)
//
#include <hip/hip_runtime.h>
#include <hip/hip_bf16.h>

// ---------------------------------------------------------------------------
// StyleEncoder pipeline for MI355X (gfx950).  R18 (base: R17, 2060us):
//  - Encoder k_sub2: PAIRED-TILE block (1024 thr = 2 x 8-wave groups, each
//    owning one M=64 tile; group B phase-shifted one round).  Breaks the
//    2-blocks/CU phase convoy R17 counters identified (MfmaUtil 38% == pure
//    convoy: both co-resident blocks run MFMA phases simultaneously).
//    Per-group phase code is verbatim R17 k_sub<64> -> bit-identical.
//    LDS 2x73792 = 147584 B, 1 block/CU, launch_bounds(1024,4) (128-reg cap).
//  - Postnet k_sub16, k_lnc, k_vq lane-pair: unchanged from R17.
// All inputs fp32; d_out fp32: out @0, vq_loss @2097152, idx @2097153.
// ---------------------------------------------------------------------------

typedef unsigned short u16;
typedef unsigned int u32;
typedef __attribute__((ext_vector_type(8))) _Float16 f16x8;
typedef __attribute__((ext_vector_type(16))) float f32x16;

#define OUT_LOSS_OFF 2097152
#define OUT_IDX_OFF  2097153

__device__ __forceinline__ void split_f16(float x, u16& h, u16& l) {
    union { _Float16 f; u16 u; } a, b;
    a.f = (_Float16)x;              // RNE f32->f16
    float hf = (float)a.f;
    b.f = (_Float16)(x - hf);       // residual, RNE to f16
    h = a.u; l = b.u;
}

__device__ __forceinline__ void gelu_pack(float v, float bb, u16* GH, u16* GL,
                                          int off) {
    const float ks = 0.5773502691896258f;
    float y = (v + bb) * ks;
    float ge = 0.5f * y * (1.0f + erff(y * 0.7071067811865476f));
    u16 h, l; split_f16(ge, h, l);
    GH[off] = h; GL[off] = l;
}

// ---------------- weight transposes -----------------------------------------
__global__ __launch_bounds__(256) void k_t_mat(const float* __restrict__ w,
                                               float* __restrict__ wt,
                                               int G, int O, int I) {
    size_t n = (size_t)G * O * I;
    for (size_t i = (size_t)blockIdx.x * 256 + threadIdx.x; i < n;
         i += (size_t)gridDim.x * 256) {
        int ci = (int)(i % I);
        int o  = (int)((i / I) % O);
        int g  = (int)(i / ((size_t)I * O));
        wt[((size_t)g * I + ci) * O + o] = w[i];
    }
}

// ---- W1 -> B-fragment layout, split hi/lo f16.
// idx = ((((s*3+k3)*16+kb)*16+nt)*64+L)*8+j ; val = w1[s][oc][c][k3]
// oc = nt*32+(L&31), c = kb*16+((L>>5)<<3)+j
__global__ __launch_bounds__(256) void k_t_w1mf(const float* __restrict__ w,
                                                u16* __restrict__ BH,
                                                u16* __restrict__ BL, int S) {
    size_t N = (size_t)S * 3 * 16 * 16 * 64 * 8;
    for (size_t i = (size_t)blockIdx.x * 256 + threadIdx.x; i < N;
         i += (size_t)gridDim.x * 256) {
        int j = (int)(i & 7); size_t r = i >> 3;
        int L = (int)(r & 63); r >>= 6;
        int nt = (int)(r & 15); r >>= 4;
        int kb = (int)(r & 15); r >>= 4;
        int k3 = (int)(r % 3); int s = (int)(r / 3);
        int oc = nt * 32 + (L & 31);
        int c = kb * 16 + ((L >> 5) << 3) + j;
        float v = w[(((size_t)s * 512 + oc) * 256 + c) * 3 + k3];
        u16 h, l; split_f16(v, h, l);
        BH[i] = h; BL[i] = l;
    }
}

// ---- W2 -> B-fragment layout. idx = (((s*32+kb)*8+nt)*64+L)*8+j
__global__ __launch_bounds__(256) void k_t_w2mf(const float* __restrict__ w,
                                                u16* __restrict__ BH,
                                                u16* __restrict__ BL, int S) {
    size_t N = (size_t)S * 32 * 8 * 64 * 8;
    for (size_t i = (size_t)blockIdx.x * 256 + threadIdx.x; i < N;
         i += (size_t)gridDim.x * 256) {
        int j = (int)(i & 7);
        int L = (int)((i >> 3) & 63);
        int nt = (int)((i >> 9) & 7);
        int kb = (int)((i >> 12) & 31);
        int s = (int)(i >> 17);
        int oc = nt * 32 + (L & 31);
        int ic = kb * 16 + ((L >> 5) << 3) + j;
        float v = w[((size_t)s * 256 + oc) * 512 + ic];
        u16 h, l; split_f16(v, h, l);
        BH[i] = h; BL[i] = l;
    }
}

// ---- post conv W [256 oc][256 c][3 k3] -> B-frag (O=256, K=768).
__global__ __launch_bounds__(256) void k_t_wpmf(const float* __restrict__ w,
                                                u16* __restrict__ BH,
                                                u16* __restrict__ BL) {
    int i = blockIdx.x * 256 + threadIdx.x;   // N = 196608, grid 768
    int j = i & 7;
    int L = (i >> 3) & 63;
    int nt = (i >> 9) & 7;
    int kb = (i >> 12) & 15;
    int k3 = i >> 16;
    int oc = nt * 32 + (L & 31);
    int c = kb * 16 + ((L >> 5) << 3) + j;
    float v = w[((size_t)oc * 256 + c) * 3 + k3];
    u16 h, l; split_f16(v, h, l);
    BH[i] = h; BL[i] = l;
}

// ---------------- pointwise conv (+ optional column stats) ------------------
template <int CIN, int COUT, int CHUNK, bool STATS>
__global__ __launch_bounds__(256) void k_pw(const float* __restrict__ x,
                                            const float* __restrict__ wt,
                                            const float* __restrict__ bias,
                                            const float* __restrict__ mask,
                                            float* __restrict__ y,
                                            float* __restrict__ MM,
                                            float* __restrict__ IV, int T) {
    extern __shared__ float X[];
    constexpr int NG = COUT / CHUNK;
    __shared__ float rs[64 * NG], rs2[64 * NG];
    const int b = blockIdx.y, t0 = blockIdx.x * 64;
    for (int i = threadIdx.x; i < CIN * 64; i += 256) {
        int ci = i >> 6, j = i & 63;
        X[i] = x[((size_t)b * CIN + ci) * T + t0 + j];
    }
    __syncthreads();
    const int tl = threadIdx.x & 63;
    const int g = __builtin_amdgcn_readfirstlane((int)(threadIdx.x >> 6));
    float acc[CHUNK];
#pragma unroll
    for (int o = 0; o < CHUNK; o++) acc[o] = 0.f;
    for (int i = 0; i < CIN; i++) {
        float xv = X[i * 64 + tl];
        const float* wr = wt + (size_t)i * COUT + g * CHUNK;
#pragma unroll
        for (int o = 0; o < CHUNK; o++) acc[o] = fmaf(wr[o], xv, acc[o]);
    }
    float mk = mask ? mask[(size_t)b * T + t0 + tl] : 1.0f;
    float s = 0.f, s2 = 0.f;
#pragma unroll
    for (int o = 0; o < CHUNK; o++) {
        int oc = g * CHUNK + o;
        float val = (acc[o] + bias[oc]) * mk;
        y[((size_t)b * COUT + oc) * T + t0 + tl] = val;
        s += val; s2 += val * val;
    }
    if constexpr (STATS) {
        rs[g * 64 + tl] = s; rs2[g * 64 + tl] = s2;
        __syncthreads();
        if (threadIdx.x < 64) {
            float ss = 0.f, ss2 = 0.f;
#pragma unroll
            for (int gg = 0; gg < NG; gg++) {
                ss += rs[gg * 64 + threadIdx.x];
                ss2 += rs2[gg * 64 + threadIdx.x];
            }
            float m = ss * (1.0f / COUT);
            float var = ss2 * (1.0f / COUT) - m * m;
            MM[(size_t)b * T + t0 + threadIdx.x] = m;
            IV[(size_t)b * T + t0 + threadIdx.x] = 1.0f / sqrtf(var + 1e-5f);
        }
    }
}

// ---------------- encoder paired-tile sub-block (M=64 x 2 tiles) ------------
// 1024 thr = 2 groups x 8 waves.  Group g owns tile t0 = bx*128 + g*64 with
// its own 73792-B LDS context.  Group 1 runs the phase sequence one round
// behind group 0, so MFMA phases of one group overlap VALU/pack phases of
// the other (breaks the 2-block convoy).  Phase code == R17 k_sub<64>.
__global__ __launch_bounds__(1024, 4) void k_sub2(
    const float* __restrict__ xin, float* __restrict__ xout,
    const float* __restrict__ MMi, const float* __restrict__ IVi,
    const float* __restrict__ lng, const float* __restrict__ lnb,
    const u16* __restrict__ B1H, const u16* __restrict__ B1L,
    const float* __restrict__ b1,
    const u16* __restrict__ B2H, const u16* __restrict__ B2L,
    const float* __restrict__ b2, const float* __restrict__ mask,
    float* __restrict__ MMo, float* __restrict__ IVo, int T) {
    __shared__ __align__(16) char smem[147584];
    const int grp = (int)(threadIdx.x >> 9);     // 0 or 1
    const int tid = (int)(threadIdx.x & 511);
    char* basep = smem + (size_t)grp * 73792;
    u16* LH = (u16*)basep;                       // [66][264] u16
    u16* LL = (u16*)(basep + 34848);
    u16* GH = (u16*)basep;                       // overlay [64][264]
    u16* GL = (u16*)(basep + 34848);
    float* SO = (float*)basep;                   // overlay [64][260] f32
    float* rs  = (float*)(basep + 69696);        // 512 f32
    float* rs2 = (float*)(basep + 71744);        // 512 f32

    const int b = blockIdx.y;
    const int t0 = blockIdx.x * 128 + grp * 64;
    const size_t xoff = (size_t)b * 256 * T;
    const size_t bT = (size_t)b * T;

    const int lane = tid & 63;
    const int w = tid >> 6;
    const int arow = lane & 31;
    const int acol = (lane >> 5) << 3;
    const int thalf = (lane >> 5) << 2;
    const int oc_l = w * 32 + (lane & 31);
    const u16* b1h0 = B1H + (size_t)w * 512 + (size_t)lane * 8;        // nt=w
    const u16* b1l0 = B1L + (size_t)w * 512 + (size_t)lane * 8;
    const u16* b1h1 = B1H + (size_t)(8 + w) * 512 + (size_t)lane * 8;  // nt=8+w
    const u16* b1l1 = B1L + (size_t)(8 + w) * 512 + (size_t)lane * 8;
    const u16* b2h = B2H + (size_t)w * 512 + (size_t)lane * 8;
    const u16* b2l = B2L + (size_t)w * 512 + (size_t)lane * 8;

    f32x16 c0[2], c1[2];

    // ---- phase macros (verbatim R17 k_sub<64> bodies, M=64 constants) ----
#define PH_STAGE do {                                                         \
        int jj = tid & 63;                                                    \
        int cg = tid >> 6;                                                    \
        int t = t0 - 2 + jj;                                                  \
        bool ok = (t >= 0);                                                   \
        float m = ok ? MMi[bT + t] : 0.f;                                     \
        float v = ok ? IVi[bT + t] : 0.f;                                     \
        _Pragma("unroll")                                                     \
        for (int i = 0; i < 32; i++) {                                        \
            int c = cg + i * 8;                                               \
            float xv = ok ? xin[xoff + (size_t)c * T + t] : 0.f;              \
            float ln = ok ? ((xv - m) * v * lng[c] + lnb[c]) : 0.f;           \
            u16 h, l; split_f16(ln, h, l);                                    \
            LH[jj * 264 + c] = h; LL[jj * 264 + c] = l;                       \
        }                                                                     \
        int j2 = 64 + (tid >> 8);                                             \
        int c2 = tid & 255;                                                   \
        int t2 = t0 + 62 + (tid >> 8);                                        \
        float m2 = MMi[bT + t2], v2 = IVi[bT + t2];                           \
        float x2 = xin[xoff + (size_t)c2 * T + t2];                           \
        float ln2 = (x2 - m2) * v2 * lng[c2] + lnb[c2];                       \
        u16 h2, l2; split_f16(ln2, h2, l2);                                   \
        LH[j2 * 264 + c2] = h2; LL[j2 * 264 + c2] = l2;                       \
    } while (0)

#define PH_CONV1 do {                                                         \
        _Pragma("unroll")                                                     \
        for (int m = 0; m < 2; m++)                                           \
            _Pragma("unroll")                                                 \
            for (int r = 0; r < 16; r++) { c0[m][r] = 0.f; c1[m][r] = 0.f; }  \
        __builtin_amdgcn_s_setprio(1);                                        \
        _Pragma("unroll 2")                                                   \
        for (int kk = 0; kk < 48; kk++) {                                     \
            int k3 = kk >> 4, kb = kk & 15;                                   \
            f16x8 bh0 = *(const f16x8*)(b1h0 + (size_t)kk * 8192);            \
            f16x8 bl0 = *(const f16x8*)(b1l0 + (size_t)kk * 8192);            \
            f16x8 bh1 = *(const f16x8*)(b1h1 + (size_t)kk * 8192);            \
            f16x8 bl1 = *(const f16x8*)(b1l1 + (size_t)kk * 8192);            \
            f16x8 ah[2], al[2];                                               \
            _Pragma("unroll")                                                 \
            for (int m = 0; m < 2; m++) {                                     \
                int ao = (m * 32 + arow + k3) * 264 + kb * 16 + acol;         \
                ah[m] = *(const f16x8*)&LH[ao];                               \
                al[m] = *(const f16x8*)&LL[ao];                               \
            }                                                                 \
            _Pragma("unroll")                                                 \
            for (int m = 0; m < 2; m++) {                                     \
                c0[m] = __builtin_amdgcn_mfma_f32_32x32x16_f16(ah[m], bh0, c0[m], 0, 0, 0); \
                c1[m] = __builtin_amdgcn_mfma_f32_32x32x16_f16(ah[m], bh1, c1[m], 0, 0, 0); \
            }                                                                 \
            _Pragma("unroll")                                                 \
            for (int m = 0; m < 2; m++) {                                     \
                c0[m] = __builtin_amdgcn_mfma_f32_32x32x16_f16(ah[m], bl0, c0[m], 0, 0, 0); \
                c1[m] = __builtin_amdgcn_mfma_f32_32x32x16_f16(ah[m], bl1, c1[m], 0, 0, 0); \
            }                                                                 \
            _Pragma("unroll")                                                 \
            for (int m = 0; m < 2; m++) {                                     \
                c0[m] = __builtin_amdgcn_mfma_f32_32x32x16_f16(al[m], bh0, c0[m], 0, 0, 0); \
                c1[m] = __builtin_amdgcn_mfma_f32_32x32x16_f16(al[m], bh1, c1[m], 0, 0, 0); \
            }                                                                 \
        }                                                                     \
        __builtin_amdgcn_s_setprio(0);                                        \
    } while (0)

#define PH_PACK0 do {                                                         \
        float bb = b1[oc_l];                                                  \
        _Pragma("unroll")                                                     \
        for (int m = 0; m < 2; m++)                                           \
            _Pragma("unroll")                                                 \
            for (int r = 0; r < 16; r++) {                                    \
                int trow = m * 32 + thalf + ((r >> 2) << 3) + (r & 3);        \
                gelu_pack(c0[m][r], bb, GH, GL, trow * 264 + oc_l);           \
            }                                                                 \
    } while (0)

#define PH_PACK1 do {                                                         \
        float bb = b1[256 + oc_l];                                            \
        _Pragma("unroll")                                                     \
        for (int m = 0; m < 2; m++)                                           \
            _Pragma("unroll")                                                 \
            for (int r = 0; r < 16; r++) {                                    \
                int trow = m * 32 + thalf + ((r >> 2) << 3) + (r & 3);        \
                gelu_pack(c1[m][r], bb, GH, GL, trow * 264 + oc_l);           \
            }                                                                 \
    } while (0)

#define PH_CONV2(IOFF, ZERO) do {                                             \
        if (ZERO) {                                                           \
            _Pragma("unroll")                                                 \
            for (int m = 0; m < 2; m++)                                       \
                _Pragma("unroll")                                             \
                for (int r = 0; r < 16; r++) c0[m][r] = 0.f;                  \
        }                                                                     \
        __builtin_amdgcn_s_setprio(1);                                        \
        _Pragma("unroll 2")                                                   \
        for (int i = 0; i < 16; i++) {                                        \
            f16x8 bh2 = *(const f16x8*)(b2h + (size_t)(IOFF + i) * 4096);     \
            f16x8 bl2 = *(const f16x8*)(b2l + (size_t)(IOFF + i) * 4096);     \
            f16x8 gh[2], gl[2];                                               \
            _Pragma("unroll")                                                 \
            for (int m = 0; m < 2; m++) {                                     \
                int go = (m * 32 + arow) * 264 + i * 16 + acol;               \
                gh[m] = *(const f16x8*)&GH[go];                               \
                gl[m] = *(const f16x8*)&GL[go];                               \
            }                                                                 \
            _Pragma("unroll")                                                 \
            for (int m = 0; m < 2; m++)                                       \
                c0[m] = __builtin_amdgcn_mfma_f32_32x32x16_f16(gh[m], bh2, c0[m], 0, 0, 0); \
            _Pragma("unroll")                                                 \
            for (int m = 0; m < 2; m++)                                       \
                c0[m] = __builtin_amdgcn_mfma_f32_32x32x16_f16(gh[m], bl2, c0[m], 0, 0, 0); \
            _Pragma("unroll")                                                 \
            for (int m = 0; m < 2; m++)                                       \
                c0[m] = __builtin_amdgcn_mfma_f32_32x32x16_f16(gl[m], bh2, c0[m], 0, 0, 0); \
        }                                                                     \
        __builtin_amdgcn_s_setprio(0);                                        \
    } while (0)

#define PH_SOUT do {                                                          \
        _Pragma("unroll")                                                     \
        for (int m = 0; m < 2; m++)                                           \
            _Pragma("unroll")                                                 \
            for (int r = 0; r < 16; r++) {                                    \
                int trow = m * 32 + thalf + ((r >> 2) << 3) + (r & 3);        \
                SO[trow * 260 + oc_l] = c0[m][r];                             \
            }                                                                 \
    } while (0)

#define PH_EPI do {                                                           \
        int t = tid & 63, cg = tid >> 6;                                      \
        float mk = mask[bT + t0 + t];                                         \
        float s = 0.f, s2 = 0.f;                                              \
        _Pragma("unroll")                                                     \
        for (int i = 0; i < 32; i++) {                                        \
            int c = cg * 32 + i;                                              \
            size_t adr = xoff + (size_t)c * T + t0 + t;                       \
            float val = (xin[adr] + SO[t * 260 + c] + b2[c]) * mk;            \
            xout[adr] = val;                                                  \
            s += val; s2 += val * val;                                        \
        }                                                                     \
        rs[tid] = s; rs2[tid] = s2;                                           \
    } while (0)

#define PH_STATS do {                                                         \
        if (tid < 64) {                                                       \
            float ss = 0.f, ss2 = 0.f;                                        \
            _Pragma("unroll")                                                 \
            for (int k = 0; k < 8; k++) {                                     \
                ss += rs[k * 64 + tid]; ss2 += rs2[k * 64 + tid];             \
            }                                                                 \
            float m = ss * (1.0f / 256.0f);                                   \
            float var = ss2 * (1.0f / 256.0f) - m * m;                        \
            MMo[bT + t0 + tid] = m;                                           \
            IVo[bT + t0 + tid] = 1.0f / sqrtf(var + 1e-5f);                   \
        }                                                                     \
    } while (0)

    // ---- round ladder: group 1 runs one round behind group 0 ----
    if (grp == 0) PH_STAGE;
    __syncthreads();                       // r0
    if (grp == 0) PH_CONV1; else PH_STAGE;
    __syncthreads();                       // r1
    if (grp == 0) PH_PACK0; else PH_CONV1;
    __syncthreads();                       // r2
    if (grp == 0) PH_CONV2(0, true); else PH_PACK0;
    __syncthreads();                       // r3
    if (grp == 0) PH_PACK1; else PH_CONV2(0, true);
    __syncthreads();                       // r4
    if (grp == 0) PH_CONV2(16, false); else PH_PACK1;
    __syncthreads();                       // r5
    if (grp == 0) PH_SOUT; else PH_CONV2(16, false);
    __syncthreads();                       // r6
    if (grp == 0) { PH_EPI; } else PH_SOUT;
    __syncthreads();                       // r7
    if (grp == 0) { PH_STATS; } else { PH_EPI; }
    __syncthreads();                       // r8
    if (grp == 1) PH_STATS;

#undef PH_STAGE
#undef PH_CONV1
#undef PH_PACK0
#undef PH_PACK1
#undef PH_CONV2
#undef PH_SOUT
#undef PH_EPI
#undef PH_STATS
}

// ---------------- postnet fused sub-block: M=32, 1024 thr / 16 waves --------
// grid = 256 = 1 block/CU -> LDS is free.  Full-K G [32][536] (both conv1
// phases at once): single all-wave pack, conv2 split across all 16 waves
// (w<8: ic 0..255, w>=8: ic 256..511).  Dual SOUT buffers (no RMW, one
// fewer barrier).  6 barriers.
__global__ __launch_bounds__(1024, 4) void k_sub16(
    const float* __restrict__ xin, float* __restrict__ xout,
    const float* __restrict__ MMi, const float* __restrict__ IVi,
    const float* __restrict__ lng, const float* __restrict__ lnb,
    const u16* __restrict__ B1H, const u16* __restrict__ B1L,
    const float* __restrict__ b1,
    const u16* __restrict__ B2H, const u16* __restrict__ B2L,
    const float* __restrict__ b2, const float* __restrict__ mask,
    float* __restrict__ MMo, float* __restrict__ IVo, int T) {
    __shared__ __align__(16) char smem[76800];
    u16* LH = (u16*)smem;                     // [34][264] u16 = 17952 B
    u16* LL = (u16*)(smem + 17952);           // 17952  (total 35904)
    u16* GH = (u16*)smem;                     // overlay [32][536] = 34304 B
    u16* GL = (u16*)(smem + 34304);           // 34304  (total 68608)
    float* SOUT  = (float*)smem;              // overlay [32][260] f32 = 33280
    float* SOUT2 = (float*)(smem + 34304);    // overlay on GL, 33280
    float* rs  = (float*)(smem + 68608);      // 1024 f32
    float* rs2 = (float*)(smem + 72704);      // 1024 f32

    const int tid = threadIdx.x;
    const int b = blockIdx.y, t0 = blockIdx.x * 32;
    const size_t xoff = (size_t)b * 256 * T;
    const size_t bT = (size_t)b * T;

    // ---- stage
    {
        int jj = tid & 31;
        int cg = tid >> 5;                    // 0..31
        int t = t0 - 2 + jj;
        bool ok = (t >= 0);
        float m = ok ? MMi[bT + t] : 0.f;
        float v = ok ? IVi[bT + t] : 0.f;
#pragma unroll
        for (int i = 0; i < 8; i++) {
            int c = cg + i * 32;
            float xv = ok ? xin[xoff + (size_t)c * T + t] : 0.f;
            float ln = ok ? ((xv - m) * v * lng[c] + lnb[c]) : 0.f;
            u16 h, l; split_f16(ln, h, l);
            LH[jj * 264 + c] = h; LL[jj * 264 + c] = l;
        }
        if (tid < 512) {
            int j2 = 32 + (tid >> 8);
            int c2 = tid & 255;
            int t2 = t0 + 30 + (tid >> 8);
            float ln2 = (xin[xoff + (size_t)c2 * T + t2] - MMi[bT + t2]) *
                        IVi[bT + t2] * lng[c2] + lnb[c2];
            u16 h2, l2; split_f16(ln2, h2, l2);
            LH[j2 * 264 + c2] = h2; LL[j2 * 264 + c2] = l2;
        }
    }
    __syncthreads();                                   // B1

    const int lane = tid & 63;
    const int w = tid >> 6;                            // 0..15
    const int arow = lane & 31;
    const int acol = (lane >> 5) << 3;
    const int thalf = (lane >> 5) << 2;
    const int oc_l = w * 32 + (lane & 31);             // 0..511
    const u16* b1h = B1H + (size_t)w * 512 + (size_t)lane * 8;   // nt = w
    const u16* b1l = B1L + (size_t)w * 512 + (size_t)lane * 8;

    // ---- conv1: one n-tile per wave (144 MFMA)
    f32x16 cc;
#pragma unroll
    for (int r = 0; r < 16; r++) cc[r] = 0.f;
    __builtin_amdgcn_s_setprio(1);
#pragma unroll 4
    for (int kk = 0; kk < 48; kk++) {
        int k3 = kk >> 4, kb = kk & 15;
        int ao = (arow + k3) * 264 + kb * 16 + acol;
        f16x8 ah = *(const f16x8*)&LH[ao];
        f16x8 al = *(const f16x8*)&LL[ao];
        f16x8 bh = *(const f16x8*)(b1h + (size_t)kk * 8192);
        f16x8 bl = *(const f16x8*)(b1l + (size_t)kk * 8192);
        cc = __builtin_amdgcn_mfma_f32_32x32x16_f16(ah, bh, cc, 0, 0, 0);
        cc = __builtin_amdgcn_mfma_f32_32x32x16_f16(ah, bl, cc, 0, 0, 0);
        cc = __builtin_amdgcn_mfma_f32_32x32x16_f16(al, bh, cc, 0, 0, 0);
    }
    __builtin_amdgcn_s_setprio(0);
    __syncthreads();                                   // B2: LH/LL dead

    // ---- pack: ALL 16 waves write their 32 oc columns of the full-K G
    {
        float bb = b1[oc_l];
#pragma unroll
        for (int r = 0; r < 16; r++) {
            int trow = thalf + ((r >> 2) << 3) + (r & 3);
            gelu_pack(cc[r], bb, GH, GL, trow * 536 + oc_l);
        }
    }
    __syncthreads();                                   // B3: G visible

    // ---- conv2: all 16 waves.  wave w: n-tile w&7, ic-half w>>3.
    const int nt2 = w & 7;
    const int ih = w >> 3;
    const u16* b2h = B2H + (size_t)nt2 * 512 + (size_t)lane * 8;
    const u16* b2l = B2L + (size_t)nt2 * 512 + (size_t)lane * 8;
#pragma unroll
    for (int r = 0; r < 16; r++) cc[r] = 0.f;
    __builtin_amdgcn_s_setprio(1);
#pragma unroll 4
    for (int i = 0; i < 16; i++) {
        int ii = ih * 16 + i;
        int go = arow * 536 + ii * 16 + acol;
        f16x8 gh = *(const f16x8*)&GH[go];
        f16x8 gl = *(const f16x8*)&GL[go];
        f16x8 bh2 = *(const f16x8*)(b2h + (size_t)ii * 4096);
        f16x8 bl2 = *(const f16x8*)(b2l + (size_t)ii * 4096);
        cc = __builtin_amdgcn_mfma_f32_32x32x16_f16(gh, bh2, cc, 0, 0, 0);
        cc = __builtin_amdgcn_mfma_f32_32x32x16_f16(gh, bl2, cc, 0, 0, 0);
        cc = __builtin_amdgcn_mfma_f32_32x32x16_f16(gl, bh2, cc, 0, 0, 0);
    }
    __builtin_amdgcn_s_setprio(0);
    __syncthreads();                                   // B4: all G reads done

    // ---- SOUT dual-buffer write (no RMW, no extra barrier)
    if (w < 8) {
#pragma unroll
        for (int r = 0; r < 16; r++) {
            int trow = thalf + ((r >> 2) << 3) + (r & 3);
            SOUT[trow * 260 + oc_l] = cc[r];
        }
    } else {
        int oc2 = nt2 * 32 + (lane & 31);
#pragma unroll
        for (int r = 0; r < 16; r++) {
            int trow = thalf + ((r >> 2) << 3) + (r & 3);
            SOUT2[trow * 260 + oc2] = cc[r];
        }
    }
    __syncthreads();                                   // B5
    {
        int t = tid & 31, cg = tid >> 5;               // cg 0..31
        float mk = mask[bT + t0 + t];
        float s = 0.f, s2 = 0.f;
#pragma unroll
        for (int i = 0; i < 8; i++) {
            int c = cg * 8 + i;
            size_t adr = xoff + (size_t)c * T + t0 + t;
            float val = (xin[adr] + (SOUT[t * 260 + c] + SOUT2[t * 260 + c]) +
                         b2[c]) * mk;
            xout[adr] = val;
            s += val; s2 += val * val;
        }
        rs[tid] = s; rs2[tid] = s2;
    }
    __syncthreads();                                   // B6
    if (tid < 32) {
        float ss = 0.f, ss2 = 0.f;
#pragma unroll
        for (int k = 0; k < 32; k++) {
            ss += rs[k * 32 + tid]; ss2 += rs2[k * 32 + tid];
        }
        float m = ss * (1.0f / 256.0f);
        float var = ss2 * (1.0f / 256.0f) - m * m;
        MMo[bT + t0 + tid] = m;
        IVo[bT + t0 + tid] = 1.0f / sqrtf(var + 1e-5f);
    }
}

// ---------------- final LN*mask + causal conv via MFMA (templated M) --------
template <int M>
__global__ __launch_bounds__(512, (M == 32 ? 8 : 4)) void k_lnc(
    const float* __restrict__ xin, float* __restrict__ xout,
    const float* __restrict__ MM, const float* __restrict__ IV,
    const float* __restrict__ lg, const float* __restrict__ lb,
    const u16* __restrict__ BH, const u16* __restrict__ BL,
    const float* __restrict__ bias, const float* __restrict__ mask, int T) {
    constexpr int MT = M / 32;
    constexpr int SH = (M + 2) * 264 * 2;
    constexpr int CG = 512 / M;
    constexpr int CPT = 256 / CG;
    __shared__ __align__(16) char smem[2 * SH];
    u16* LH = (u16*)smem;
    u16* LL = (u16*)(smem + SH);
    float* SOUT = (float*)smem;               // overlay

    const int tid = threadIdx.x;
    const int b = blockIdx.y, t0 = blockIdx.x * M;
    const size_t xoff = (size_t)b * 256 * T;
    const size_t bT = (size_t)b * T;

    {   // stage: (LN(x)*mask) hi/lo
        int jj = tid & (M - 1);
        int cg = tid / M;
        int t = t0 - 2 + jj;
        bool ok = (t >= 0);
        float m = ok ? MM[bT + t] : 0.f;
        float v = ok ? IV[bT + t] : 0.f;
        float mk = ok ? mask[bT + t] : 0.f;
#pragma unroll
        for (int i = 0; i < CPT; i++) {
            int c = cg + i * CG;
            float xv = ok ? xin[xoff + (size_t)c * T + t] : 0.f;
            float ln = ok ? ((xv - m) * v * lg[c] + lb[c]) * mk : 0.f;
            u16 h, l; split_f16(ln, h, l);
            LH[jj * 264 + c] = h; LL[jj * 264 + c] = l;
        }
        int j2 = M + (tid >> 8);
        int c2 = tid & 255;
        int t2 = t0 + (M - 2) + (tid >> 8);
        float ln2 = ((xin[xoff + (size_t)c2 * T + t2] - MM[bT + t2]) *
                     IV[bT + t2] * lg[c2] + lb[c2]) * mask[bT + t2];
        u16 h2, l2; split_f16(ln2, h2, l2);
        LH[j2 * 264 + c2] = h2; LL[j2 * 264 + c2] = l2;
    }
    __syncthreads();

    const int lane = tid & 63;
    const int w = tid >> 6;
    const int arow = lane & 31;
    const int acol = (lane >> 5) << 3;
    const int thalf = (lane >> 5) << 2;
    const u16* bph = BH + (size_t)w * 512 + (size_t)lane * 8;
    const u16* bpl = BL + (size_t)w * 512 + (size_t)lane * 8;

    f32x16 aH[MT], aM[MT];
#pragma unroll
    for (int m = 0; m < MT; m++)
#pragma unroll
        for (int r = 0; r < 16; r++) { aH[m][r] = 0.f; aM[m][r] = 0.f; }
    __builtin_amdgcn_s_setprio(1);
#pragma unroll 2
    for (int kk = 0; kk < 48; kk++) {
        int k3 = kk >> 4, kb = kk & 15;
        f16x8 bh = *(const f16x8*)(bph + (size_t)kk * 4096);
        f16x8 bl = *(const f16x8*)(bpl + (size_t)kk * 4096);
        f16x8 ah[MT], al[MT];
#pragma unroll
        for (int m = 0; m < MT; m++) {
            int ao = (m * 32 + arow + k3) * 264 + kb * 16 + acol;
            ah[m] = *(const f16x8*)&LH[ao];
            al[m] = *(const f16x8*)&LL[ao];
        }
#pragma unroll
        for (int m = 0; m < MT; m++)
            aH[m] = __builtin_amdgcn_mfma_f32_32x32x16_f16(ah[m], bh, aH[m], 0, 0, 0);
#pragma unroll
        for (int m = 0; m < MT; m++)
            aM[m] = __builtin_amdgcn_mfma_f32_32x32x16_f16(ah[m], bl, aM[m], 0, 0, 0);
#pragma unroll
        for (int m = 0; m < MT; m++)
            aM[m] = __builtin_amdgcn_mfma_f32_32x32x16_f16(al[m], bh, aM[m], 0, 0, 0);
    }
    __builtin_amdgcn_s_setprio(0);
    __syncthreads();  // all LH/LL reads done before SOUT overlay
    {
        int oc = w * 32 + (lane & 31);
#pragma unroll
        for (int m = 0; m < MT; m++)
#pragma unroll
            for (int r = 0; r < 16; r++) {
                int trow = m * 32 + thalf + ((r >> 2) << 3) + (r & 3);
                SOUT[trow * 260 + oc] = aH[m][r] + aM[m][r];
            }
    }
    __syncthreads();
    {
        int t = tid & (M - 1), cg = tid / M;
        float mk = mask[bT + t0 + t];
#pragma unroll
        for (int i = 0; i < CPT; i++) {
            int c = cg * CPT + i;
            xout[xoff + (size_t)c * T + t0 + t] =
                (SOUT[t * 260 + c] + bias[c]) * mk;
        }
    }
}

// ---------------- group-by-segments (scatter mean) --------------------------
__global__ __launch_bounds__(256) void k_counts(const int* __restrict__ m2p,
                                                int* __restrict__ cnt) {
    __shared__ int c[512];
    int b = blockIdx.x;
    for (int i = threadIdx.x; i < 512; i += 256) c[i] = 0;
    __syncthreads();
    for (int t = threadIdx.x; t < 2048; t += 256) {
        int p = m2p[b * 2048 + t];
        if (p >= 1 && p <= 512) atomicAdd(&c[p - 1], 1);
    }
    __syncthreads();
    for (int i = threadIdx.x; i < 512; i += 256) cnt[b * 512 + i] = c[i];
}

__global__ __launch_bounds__(256) void k_scatter(const float* __restrict__ h,
                                                 const int* __restrict__ m2p,
                                                 float* __restrict__ g) {
    extern __shared__ float sm[];
    float* HT = sm;
    int* ph = (int*)(sm + 256 * 65);
    int b = blockIdx.y, t0 = blockIdx.x * 64;
    if (threadIdx.x < 64) ph[threadIdx.x] = m2p[b * 2048 + t0 + threadIdx.x];
    for (int i = threadIdx.x; i < 256 * 64; i += 256) {
        int c = i >> 6, j = i & 63;
        HT[c * 65 + j] = h[((size_t)b * 256 + c) * 2048 + t0 + j];
    }
    __syncthreads();
    int c = threadIdx.x;
    float run = 0.f;
    int cur = ph[0];
    for (int j = 0; j < 64; j++) {
        int p = ph[j];
        if (p != cur) {
            if (cur >= 1 && cur <= 512)
                atomicAdd(&g[((size_t)b * 256 + c) * 512 + cur - 1], run);
            run = 0.f;
            cur = p;
        }
        run += HT[c * 65 + j];
    }
    if (cur >= 1 && cur <= 512)
        atomicAdd(&g[((size_t)b * 256 + c) * 512 + cur - 1], run);
}

__global__ __launch_bounds__(512) void k_postprep(float* __restrict__ g,
                                                  const int* __restrict__ cnt,
                                                  float* __restrict__ MM,
                                                  float* __restrict__ IV) {
    int b = blockIdx.x, l = threadIdx.x;
    int c1 = cnt[b * 512 + l];
    if (c1 < 1) c1 = 1;
    float rc = 1.0f / (float)c1;
    float s = 0.f, s2 = 0.f;
    for (int c = 0; c < 256; c++) {
        size_t idx = ((size_t)b * 256 + c) * 512 + l;
        float v = g[idx] * rc;
        g[idx] = v;
        s += v; s2 += v * v;
    }
    float m = s * (1.0f / 256.0f);
    float var = s2 * (1.0f / 256.0f) - m * m;
    MM[(size_t)b * 512 + l] = m;
    IV[(size_t)b * 512 + l] = 1.0f / sqrtf(var + 1e-5f);
}

// ---------------- VQ (lane-pair K-split) ------------------------------------
__global__ __launch_bounds__(256) void k_vq(const float* __restrict__ z,
                                            const float* __restrict__ cb,
                                            int* __restrict__ idxout,
                                            float* __restrict__ out,
                                            float* __restrict__ lossacc) {
    int n2 = blockIdx.x * 256 + threadIdx.x;   // 16384 total (grid 64)
    int n = n2 >> 1;                           // (b,l) work item
    int half = n2 & 1;                         // codebook half
    int b = n >> 9, l = n & 511;
    float zr[64];
#pragma unroll
    for (int c = 0; c < 64; c++) zr[c] = z[((size_t)b * 64 + c) * 512 + l];
    float best = 3.4e38f;
    int bi = 0;
    int k0 = half * 64;
    for (int k = k0; k < k0 + 64; k++) {
        const float* cr = cb + k * 64;
        float d = 0.f;
#pragma unroll
        for (int c = 0; c < 64; c++) {
            float t = zr[c] - cr[c];
            d = fmaf(t, t, d);
        }
        if (d < best) { best = d; bi = k; }
    }
    // combine across the lane pair (first-min semantics: lower k wins ties)
    float bestO = __shfl_xor(best, 1);
    int biO = __shfl_xor(bi, 1);
    if (bestO < best || (bestO == best && biO < bi)) { best = bestO; bi = biO; }
    if (half == 0) {
        idxout[n] = bi;
        out[OUT_IDX_OFF + n] = (float)bi;
        atomicAdd(lossacc, best);
    }
}

__global__ void k_loss(const float* __restrict__ acc, float* __restrict__ out) {
    if (threadIdx.x == 0 && blockIdx.x == 0)
        out[OUT_LOSS_OFF] = 0.25f * acc[0] * (1.0f / 524288.0f);
}

// ---------------- proj_out --------------------------------------------------
__global__ __launch_bounds__(256) void k_projout(const float* __restrict__ cb,
                                                 const int* __restrict__ idx,
                                                 const float* __restrict__ wt,
                                                 const float* __restrict__ bias,
                                                 float* __restrict__ out) {
    __shared__ float Q[64 * 64];
    __shared__ int ids[64];
    int b = blockIdx.y, l0 = blockIdx.x * 64;
    if (threadIdx.x < 64) ids[threadIdx.x] = idx[b * 512 + l0 + threadIdx.x];
    __syncthreads();
    for (int i = threadIdx.x; i < 4096; i += 256) {
        int c = i >> 6, l = i & 63;
        Q[c * 64 + l] = cb[ids[l] * 64 + c];
    }
    __syncthreads();
    int tl = threadIdx.x & 63;
    int g = __builtin_amdgcn_readfirstlane((int)(threadIdx.x >> 6));
    float acc[64];
#pragma unroll
    for (int o = 0; o < 64; o++) acc[o] = 0.f;
    for (int i = 0; i < 64; i++) {
        float xv = Q[i * 64 + tl];
        const float* wr = wt + i * 256 + g * 64;
#pragma unroll
        for (int o = 0; o < 64; o++) acc[o] = fmaf(wr[o], xv, acc[o]);
    }
#pragma unroll
    for (int o = 0; o < 64; o++) {
        int oc = g * 64 + o;
        out[(size_t)b * 131072 + (size_t)oc * 512 + l0 + tl] = acc[o] + bias[oc];
    }
}

// ---------------------------------------------------------------------------
extern "C" void kernel_launch(void* const* d_in, const int* in_sizes, int n_in,
                              void* d_out, int out_size, void* d_ws, size_t ws_size,
                              hipStream_t stream) {
    (void)in_sizes; (void)n_in; (void)out_size; (void)ws_size;
    const float* x          = (const float*)d_in[0];
    const float* in_np      = (const float*)d_in[1];
    const int*   mel2ph     = (const int*)d_in[2];
    const float* ph_np      = (const float*)d_in[3];
    const float* conv_in_w  = (const float*)d_in[4];
    const float* conv_in_b  = (const float*)d_in[5];
    const float* e_ln_g = (const float*)d_in[6];
    const float* e_ln_b = (const float*)d_in[7];
    const float* e_w1   = (const float*)d_in[8];
    const float* e_b1   = (const float*)d_in[9];
    const float* e_w2   = (const float*)d_in[10];
    const float* e_b2   = (const float*)d_in[11];
    const float* e_lg   = (const float*)d_in[12];
    const float* e_lb   = (const float*)d_in[13];
    const float* e_pw   = (const float*)d_in[14];
    const float* e_pb   = (const float*)d_in[15];
    const float* p_ln_g = (const float*)d_in[16];
    const float* p_ln_b = (const float*)d_in[17];
    const float* p_w1   = (const float*)d_in[18];
    const float* p_b1   = (const float*)d_in[19];
    const float* p_w2   = (const float*)d_in[20];
    const float* p_b2   = (const float*)d_in[21];
    const float* p_lg   = (const float*)d_in[22];
    const float* p_lb   = (const float*)d_in[23];
    const float* p_pw   = (const float*)d_in[24];
    const float* p_pb   = (const float*)d_in[25];
    const float* proj_in_w  = (const float*)d_in[26];
    const float* proj_in_b  = (const float*)d_in[27];
    const float* proj_out_w = (const float*)d_in[28];
    const float* proj_out_b = (const float*)d_in[29];
    const float* codebook   = (const float*)d_in[30];
    float* out = (float*)d_out;

    float* ws = (float*)d_ws;
    float* A      = ws;                        // 8388608
    float* Bb     = A + 8388608;               // 8388608
    float* CINT   = Bb + 8388608;              // 20480
    float* PINT   = CINT + 20480;              // 16384
    float* POUTT  = PINT + 16384;              // 16384
    float* Z      = POUTT + 16384;             // 524288
    float* MM0    = Z + 524288;                // 32768
    float* IV0    = MM0 + 32768;               // 32768
    float* MM1    = IV0 + 32768;               // 32768
    float* IV1    = MM1 + 32768;               // 32768
    int*   CNT    = (int*)(IV1 + 32768);       // 8192
    int*   IDX    = CNT + 8192;                // 8192
    float* LOSS   = (float*)(IDX + 8192);      // 64 (aligned pad)
    u16*   BH1E   = (u16*)(LOSS + 64);         // 3932160 each
    u16*   BL1E   = BH1E + 3932160;
    u16*   BH1P   = BL1E + 3932160;
    u16*   BL1P   = BH1P + 3932160;
    u16*   BH2E   = BL1P + 3932160;            // 1310720 each
    u16*   BL2E   = BH2E + 1310720;
    u16*   BH2P   = BL2E + 1310720;
    u16*   BL2P   = BH2P + 1310720;
    u16*   PH_E   = BL2P + 1310720;            // 196608 each
    u16*   PL_E   = PH_E + 196608;
    u16*   PH_P   = PL_E + 196608;
    u16*   PL_P   = PH_P + 196608;

    // weight prep (ws re-poisoned every call -> recompute)
    k_t_w1mf<<<dim3(4096), dim3(256), 0, stream>>>(e_w1, BH1E, BL1E, 10);
    k_t_w1mf<<<dim3(4096), dim3(256), 0, stream>>>(p_w1, BH1P, BL1P, 10);
    k_t_w2mf<<<dim3(2048), dim3(256), 0, stream>>>(e_w2, BH2E, BL2E, 10);
    k_t_w2mf<<<dim3(2048), dim3(256), 0, stream>>>(p_w2, BH2P, BL2P, 10);
    k_t_wpmf<<<dim3(768),  dim3(256), 0, stream>>>(e_pw, PH_E, PL_E);
    k_t_wpmf<<<dim3(768),  dim3(256), 0, stream>>>(p_pw, PH_P, PL_P);
    k_t_mat  <<<dim3(80),  dim3(256), 0, stream>>>(conv_in_w, CINT, 1, 256, 80);
    k_t_mat  <<<dim3(64),  dim3(256), 0, stream>>>(proj_in_w, PINT, 1, 64, 256);
    k_t_mat  <<<dim3(64),  dim3(256), 0, stream>>>(proj_out_w, POUTT, 1, 256, 64);

    const size_t sm_scat = 256 * 65 * sizeof(float) + 64 * sizeof(int);

    // ---- conv_in + mask -> A (+ LN stats for encoder layer 0)
    k_pw<80, 256, 64, true><<<dim3(32, 16), dim3(256), 80 * 64 * 4, stream>>>(
        x, CINT, conv_in_b, in_np, A, MM0, IV0, 2048);

    // ---- encoder: 10 paired-tile sub-blocks (2 x M=64), ping-pong A<->B
    float* cur = A;
    float* nxt = Bb;
    for (int s = 0; s < 10; s++) {
        float* mi = (s & 1) ? MM1 : MM0;
        float* vi = (s & 1) ? IV1 : IV0;
        float* mo = (s & 1) ? MM0 : MM1;
        float* vo = (s & 1) ? IV0 : IV1;
        k_sub2<<<dim3(16, 16), dim3(1024), 0, stream>>>(
            cur, nxt, mi, vi, e_ln_g + s * 256, e_ln_b + s * 256,
            BH1E + (size_t)s * 393216, BL1E + (size_t)s * 393216, e_b1 + s * 512,
            BH2E + (size_t)s * 131072, BL2E + (size_t)s * 131072, e_b2 + s * 256,
            in_np, mo, vo, 2048);
        float* t = cur; cur = nxt; nxt = t;
    }
    // final stats in MM0/IV0 (s=9 odd -> wrote MM0)
    k_lnc<64><<<dim3(32, 16), dim3(512), 0, stream>>>(
        cur, nxt, MM0, IV0, e_lg, e_lb, PH_E, PL_E, e_pb, in_np, 2048);

    // ---- group-by-segs: B (T=2048) -> A (compact [16,256,512])
    hipMemsetAsync(A, 0, (size_t)2097152 * 4, stream);
    hipMemsetAsync(LOSS, 0, 4, stream);
    k_counts<<<dim3(16), dim3(256), 0, stream>>>(mel2ph, CNT);
    k_scatter<<<dim3(32, 16), dim3(256), sm_scat, stream>>>(Bb, mel2ph, A);
    k_postprep<<<dim3(16), dim3(512), 0, stream>>>(A, CNT, MM0, IV0);

    // ---- postnet: 10 fused sub-blocks on T=512 (M=32, 16 waves)
    cur = A; nxt = Bb;
    for (int s = 0; s < 10; s++) {
        float* mi = (s & 1) ? MM1 : MM0;
        float* vi = (s & 1) ? IV1 : IV0;
        float* mo = (s & 1) ? MM0 : MM1;
        float* vo = (s & 1) ? IV0 : IV1;
        k_sub16<<<dim3(16, 16), dim3(1024), 0, stream>>>(
            cur, nxt, mi, vi, p_ln_g + s * 256, p_ln_b + s * 256,
            BH1P + (size_t)s * 393216, BL1P + (size_t)s * 393216, p_b1 + s * 512,
            BH2P + (size_t)s * 131072, BL2P + (size_t)s * 131072, p_b2 + s * 256,
            ph_np, mo, vo, 512);
        float* t = cur; cur = nxt; nxt = t;
    }
    k_lnc<32><<<dim3(16, 16), dim3(512), 0, stream>>>(
        cur, nxt, MM0, IV0, p_lg, p_lb, PH_P, PL_P, p_pb, ph_np, 512);

    // ---- proj_in: B -> Z [16,64,512]
    k_pw<256, 64, 16, false><<<dim3(8, 16), dim3(256), 256 * 64 * 4, stream>>>(
        Bb, PINT, proj_in_b, nullptr, Z, nullptr, nullptr, 512);

    // ---- VQ + loss + proj_out
    k_vq<<<dim3(64), dim3(256), 0, stream>>>(Z, codebook, IDX, out, LOSS);
    k_loss<<<dim3(1), dim3(64), 0, stream>>>(LOSS, out);
    k_projout<<<dim3(8, 16), dim3(256), 0, stream>>>(codebook, IDX, POUTT,
                                                     proj_out_b, out);
}

// Round 10
// 2086.537 us; speedup vs baseline: 1.0171x; 1.0171x over previous
//
#include <hip/hip_runtime.h>
#include <hip/hip_bf16.h>

// ---------------------------------------------------------------------------
// StyleEncoder pipeline for MI355X (gfx950).  R20 = R19 resubmit (previous
// bench died in container acquisition, no kernel data).
//  - Encoder k_sub128: M=128 single-tile block, 1024 thr / 16 waves, grid
//    16x16 = 256 = 1 block/CU.  Wave w owns conv1 n-tile w for 4 m-tiles:
//    B loads per 12 MFMAs halve, per-column B L2 traffic drops 4x (R18
//    analysis: within-phase stalls track the per-kk B-load chain, not phase
//    overlap -- two different overlap topologies both measured ~37% MfmaUtil).
//    Single c0[4] acc (64 AGPR peak): pack-p0 kills it for w<8 before conv2
//    reuse; w>=8 hold theirs until pack-p1 (wave-uniform branch, same regs).
//    conv2 on waves 0-7 only.  Same per-chain MFMA order -> bit-identical.
//  - Postnet k_sub16, k_lnc, k_vq lane-pair: unchanged.
// All inputs fp32; d_out fp32: out @0, vq_loss @2097152, idx @2097153.
// ---------------------------------------------------------------------------

typedef unsigned short u16;
typedef unsigned int u32;
typedef __attribute__((ext_vector_type(8))) _Float16 f16x8;
typedef __attribute__((ext_vector_type(16))) float f32x16;

#define OUT_LOSS_OFF 2097152
#define OUT_IDX_OFF  2097153

__device__ __forceinline__ void split_f16(float x, u16& h, u16& l) {
    union { _Float16 f; u16 u; } a, b;
    a.f = (_Float16)x;              // RNE f32->f16
    float hf = (float)a.f;
    b.f = (_Float16)(x - hf);       // residual, RNE to f16
    h = a.u; l = b.u;
}

__device__ __forceinline__ void gelu_pack(float v, float bb, u16* GH, u16* GL,
                                          int off) {
    const float ks = 0.5773502691896258f;
    float y = (v + bb) * ks;
    float ge = 0.5f * y * (1.0f + erff(y * 0.7071067811865476f));
    u16 h, l; split_f16(ge, h, l);
    GH[off] = h; GL[off] = l;
}

// ---------------- weight transposes -----------------------------------------
__global__ __launch_bounds__(256) void k_t_mat(const float* __restrict__ w,
                                               float* __restrict__ wt,
                                               int G, int O, int I) {
    size_t n = (size_t)G * O * I;
    for (size_t i = (size_t)blockIdx.x * 256 + threadIdx.x; i < n;
         i += (size_t)gridDim.x * 256) {
        int ci = (int)(i % I);
        int o  = (int)((i / I) % O);
        int g  = (int)(i / ((size_t)I * O));
        wt[((size_t)g * I + ci) * O + o] = w[i];
    }
}

// ---- W1 -> B-fragment layout, split hi/lo f16.
// idx = ((((s*3+k3)*16+kb)*16+nt)*64+L)*8+j ; val = w1[s][oc][c][k3]
// oc = nt*32+(L&31), c = kb*16+((L>>5)<<3)+j
__global__ __launch_bounds__(256) void k_t_w1mf(const float* __restrict__ w,
                                                u16* __restrict__ BH,
                                                u16* __restrict__ BL, int S) {
    size_t N = (size_t)S * 3 * 16 * 16 * 64 * 8;
    for (size_t i = (size_t)blockIdx.x * 256 + threadIdx.x; i < N;
         i += (size_t)gridDim.x * 256) {
        int j = (int)(i & 7); size_t r = i >> 3;
        int L = (int)(r & 63); r >>= 6;
        int nt = (int)(r & 15); r >>= 4;
        int kb = (int)(r & 15); r >>= 4;
        int k3 = (int)(r % 3); int s = (int)(r / 3);
        int oc = nt * 32 + (L & 31);
        int c = kb * 16 + ((L >> 5) << 3) + j;
        float v = w[(((size_t)s * 512 + oc) * 256 + c) * 3 + k3];
        u16 h, l; split_f16(v, h, l);
        BH[i] = h; BL[i] = l;
    }
}

// ---- W2 -> B-fragment layout. idx = (((s*32+kb)*8+nt)*64+L)*8+j
__global__ __launch_bounds__(256) void k_t_w2mf(const float* __restrict__ w,
                                                u16* __restrict__ BH,
                                                u16* __restrict__ BL, int S) {
    size_t N = (size_t)S * 32 * 8 * 64 * 8;
    for (size_t i = (size_t)blockIdx.x * 256 + threadIdx.x; i < N;
         i += (size_t)gridDim.x * 256) {
        int j = (int)(i & 7);
        int L = (int)((i >> 3) & 63);
        int nt = (int)((i >> 9) & 7);
        int kb = (int)((i >> 12) & 31);
        int s = (int)(i >> 17);
        int oc = nt * 32 + (L & 31);
        int ic = kb * 16 + ((L >> 5) << 3) + j;
        float v = w[((size_t)s * 256 + oc) * 512 + ic];
        u16 h, l; split_f16(v, h, l);
        BH[i] = h; BL[i] = l;
    }
}

// ---- post conv W [256 oc][256 c][3 k3] -> B-frag (O=256, K=768).
__global__ __launch_bounds__(256) void k_t_wpmf(const float* __restrict__ w,
                                                u16* __restrict__ BH,
                                                u16* __restrict__ BL) {
    int i = blockIdx.x * 256 + threadIdx.x;   // N = 196608, grid 768
    int j = i & 7;
    int L = (i >> 3) & 63;
    int nt = (i >> 9) & 7;
    int kb = (i >> 12) & 15;
    int k3 = i >> 16;
    int oc = nt * 32 + (L & 31);
    int c = kb * 16 + ((L >> 5) << 3) + j;
    float v = w[((size_t)oc * 256 + c) * 3 + k3];
    u16 h, l; split_f16(v, h, l);
    BH[i] = h; BL[i] = l;
}

// ---------------- pointwise conv (+ optional column stats) ------------------
template <int CIN, int COUT, int CHUNK, bool STATS>
__global__ __launch_bounds__(256) void k_pw(const float* __restrict__ x,
                                            const float* __restrict__ wt,
                                            const float* __restrict__ bias,
                                            const float* __restrict__ mask,
                                            float* __restrict__ y,
                                            float* __restrict__ MM,
                                            float* __restrict__ IV, int T) {
    extern __shared__ float X[];
    constexpr int NG = COUT / CHUNK;
    __shared__ float rs[64 * NG], rs2[64 * NG];
    const int b = blockIdx.y, t0 = blockIdx.x * 64;
    for (int i = threadIdx.x; i < CIN * 64; i += 256) {
        int ci = i >> 6, j = i & 63;
        X[i] = x[((size_t)b * CIN + ci) * T + t0 + j];
    }
    __syncthreads();
    const int tl = threadIdx.x & 63;
    const int g = __builtin_amdgcn_readfirstlane((int)(threadIdx.x >> 6));
    float acc[CHUNK];
#pragma unroll
    for (int o = 0; o < CHUNK; o++) acc[o] = 0.f;
    for (int i = 0; i < CIN; i++) {
        float xv = X[i * 64 + tl];
        const float* wr = wt + (size_t)i * COUT + g * CHUNK;
#pragma unroll
        for (int o = 0; o < CHUNK; o++) acc[o] = fmaf(wr[o], xv, acc[o]);
    }
    float mk = mask ? mask[(size_t)b * T + t0 + tl] : 1.0f;
    float s = 0.f, s2 = 0.f;
#pragma unroll
    for (int o = 0; o < CHUNK; o++) {
        int oc = g * CHUNK + o;
        float val = (acc[o] + bias[oc]) * mk;
        y[((size_t)b * COUT + oc) * T + t0 + tl] = val;
        s += val; s2 += val * val;
    }
    if constexpr (STATS) {
        rs[g * 64 + tl] = s; rs2[g * 64 + tl] = s2;
        __syncthreads();
        if (threadIdx.x < 64) {
            float ss = 0.f, ss2 = 0.f;
#pragma unroll
            for (int gg = 0; gg < NG; gg++) {
                ss += rs[gg * 64 + threadIdx.x];
                ss2 += rs2[gg * 64 + threadIdx.x];
            }
            float m = ss * (1.0f / COUT);
            float var = ss2 * (1.0f / COUT) - m * m;
            MM[(size_t)b * T + t0 + threadIdx.x] = m;
            IV[(size_t)b * T + t0 + threadIdx.x] = 1.0f / sqrtf(var + 1e-5f);
        }
    }
}

// ---------------- encoder M=128 single-tile sub-block -----------------------
// 1024 thr / 16 waves, grid (16,16) = 256 = 1 block/CU.  Wave w owns conv1
// n-tile w (oc w*32..w*32+31 across both halves) for 4 m-tiles.  conv2 on
// waves 0-7 (n-tile w, 4 m).  Single c0[4] acc: w<8 kill at pack-p0, reuse
// for conv2; w>=8 hold until pack-p1.  LDS 145472 B.  9 barriers.
__global__ __launch_bounds__(1024, 4) void k_sub128(
    const float* __restrict__ xin, float* __restrict__ xout,
    const float* __restrict__ MMi, const float* __restrict__ IVi,
    const float* __restrict__ lng, const float* __restrict__ lnb,
    const u16* __restrict__ B1H, const u16* __restrict__ B1L,
    const float* __restrict__ b1,
    const u16* __restrict__ B2H, const u16* __restrict__ B2L,
    const float* __restrict__ b2, const float* __restrict__ mask,
    float* __restrict__ MMo, float* __restrict__ IVo, int T) {
    __shared__ __align__(16) char smem[145472];
    u16* LH = (u16*)smem;                      // [130][264] u16 = 68640 B
    u16* LL = (u16*)(smem + 68640);            // 68640  (total 137280)
    u16* GH = (u16*)smem;                      // overlay [128][264] = 67584
    u16* GL = (u16*)(smem + 68640);
    float* SOUT = (float*)smem;                // overlay [128][260] f32=133120
    float* rs  = (float*)(smem + 137280);      // 1024 f32
    float* rs2 = (float*)(smem + 141376);      // 1024 f32

    const int tid = threadIdx.x;
    const int b = blockIdx.y, t0 = blockIdx.x * 128;
    const size_t xoff = (size_t)b * 256 * T;
    const size_t bT = (size_t)b * T;

    // ---- stage: LN'd x, split hi/lo f16 (rows 0..129 = t0-2 .. t0+127)
    {
        int jj = tid & 127;
        int cg = tid >> 7;                     // 0..7
        int t = t0 - 2 + jj;
        bool ok = (t >= 0);
        float m = ok ? MMi[bT + t] : 0.f;
        float v = ok ? IVi[bT + t] : 0.f;
#pragma unroll
        for (int i = 0; i < 32; i++) {
            int c = cg + i * 8;
            float xv = ok ? xin[xoff + (size_t)c * T + t] : 0.f;
            float ln = ok ? ((xv - m) * v * lng[c] + lnb[c]) : 0.f;
            u16 h, l; split_f16(ln, h, l);
            LH[jj * 264 + c] = h; LL[jj * 264 + c] = l;
        }
        if (tid < 512) {
            int j2 = 128 + (tid >> 8);
            int c2 = tid & 255;
            int t2 = t0 + 126 + (tid >> 8);
            float m2 = MMi[bT + t2], v2 = IVi[bT + t2];
            float x2 = xin[xoff + (size_t)c2 * T + t2];
            float ln2 = (x2 - m2) * v2 * lng[c2] + lnb[c2];
            u16 h2, l2; split_f16(ln2, h2, l2);
            LH[j2 * 264 + c2] = h2; LL[j2 * 264 + c2] = l2;
        }
    }
    __syncthreads();                                   // B1

    const int lane = tid & 63;
    const int w = tid >> 6;                            // 0..15
    const int arow = lane & 31;
    const int acol = (lane >> 5) << 3;
    const int thalf = (lane >> 5) << 2;
    const u16* b1h = B1H + (size_t)w * 512 + (size_t)lane * 8;   // nt = w
    const u16* b1l = B1L + (size_t)w * 512 + (size_t)lane * 8;
    const u16* b2h = B2H + (size_t)(w & 7) * 512 + (size_t)lane * 8;
    const u16* b2l = B2L + (size_t)(w & 7) * 512 + (size_t)lane * 8;

    // ---- conv1: n-tile w, 4 m-tiles.  Per-chain order (ah,bh)(ah,bl)(al,bh).
    f32x16 c0[4];
#pragma unroll
    for (int m = 0; m < 4; m++)
#pragma unroll
        for (int r = 0; r < 16; r++) c0[m][r] = 0.f;
    __builtin_amdgcn_s_setprio(1);
#pragma unroll 2
    for (int kk = 0; kk < 48; kk++) {
        int k3 = kk >> 4, kb = kk & 15;
        f16x8 bh = *(const f16x8*)(b1h + (size_t)kk * 8192);
        f16x8 bl = *(const f16x8*)(b1l + (size_t)kk * 8192);
        f16x8 ah[4], al[4];
#pragma unroll
        for (int m = 0; m < 4; m++) {
            int ao = (m * 32 + arow + k3) * 264 + kb * 16 + acol;
            ah[m] = *(const f16x8*)&LH[ao];
            al[m] = *(const f16x8*)&LL[ao];
        }
#pragma unroll
        for (int m = 0; m < 4; m++)
            c0[m] = __builtin_amdgcn_mfma_f32_32x32x16_f16(ah[m], bh, c0[m], 0, 0, 0);
#pragma unroll
        for (int m = 0; m < 4; m++)
            c0[m] = __builtin_amdgcn_mfma_f32_32x32x16_f16(ah[m], bl, c0[m], 0, 0, 0);
#pragma unroll
        for (int m = 0; m < 4; m++)
            c0[m] = __builtin_amdgcn_mfma_f32_32x32x16_f16(al[m], bh, c0[m], 0, 0, 0);
    }
    __builtin_amdgcn_s_setprio(0);
    __syncthreads();                                   // B2: LH/LL dead

    // ---- pack p0 (waves 0-7: their conv1 acc IS the p0 half); c0 dies
    if (w < 8) {
        int oc = w * 32 + (lane & 31);                 // 0..255
        float bb = b1[oc];
#pragma unroll
        for (int m = 0; m < 4; m++)
#pragma unroll
            for (int r = 0; r < 16; r++) {
                int trow = m * 32 + thalf + ((r >> 2) << 3) + (r & 3);
                gelu_pack(c0[m][r], bb, GH, GL, trow * 264 + oc);
            }
    }
    __syncthreads();                                   // B3: G p0 visible

    // ---- conv2 p0 (waves 0-7; c0 reused as conv2 acc)
    if (w < 8) {
#pragma unroll
        for (int m = 0; m < 4; m++)
#pragma unroll
            for (int r = 0; r < 16; r++) c0[m][r] = 0.f;
        __builtin_amdgcn_s_setprio(1);
#pragma unroll 2
        for (int i = 0; i < 16; i++) {
            f16x8 bh2 = *(const f16x8*)(b2h + (size_t)i * 4096);
            f16x8 bl2 = *(const f16x8*)(b2l + (size_t)i * 4096);
            f16x8 gh[4], gl[4];
#pragma unroll
            for (int m = 0; m < 4; m++) {
                int go = (m * 32 + arow) * 264 + i * 16 + acol;
                gh[m] = *(const f16x8*)&GH[go];
                gl[m] = *(const f16x8*)&GL[go];
            }
#pragma unroll
            for (int m = 0; m < 4; m++)
                c0[m] = __builtin_amdgcn_mfma_f32_32x32x16_f16(gh[m], bh2, c0[m], 0, 0, 0);
#pragma unroll
            for (int m = 0; m < 4; m++)
                c0[m] = __builtin_amdgcn_mfma_f32_32x32x16_f16(gh[m], bl2, c0[m], 0, 0, 0);
#pragma unroll
            for (int m = 0; m < 4; m++)
                c0[m] = __builtin_amdgcn_mfma_f32_32x32x16_f16(gl[m], bh2, c0[m], 0, 0, 0);
        }
        __builtin_amdgcn_s_setprio(0);
    }
    __syncthreads();                                   // B4: G p0 reads done

    // ---- pack p1 (waves 8-15: their conv1 acc is the p1 half); c0 dies
    if (w >= 8) {
        int ocp = (w - 8) * 32 + (lane & 31);          // 0..255 (col in G)
        float bb = b1[256 + ocp];
#pragma unroll
        for (int m = 0; m < 4; m++)
#pragma unroll
            for (int r = 0; r < 16; r++) {
                int trow = m * 32 + thalf + ((r >> 2) << 3) + (r & 3);
                gelu_pack(c0[m][r], bb, GH, GL, trow * 264 + ocp);
            }
    }
    __syncthreads();                                   // B5: G p1 visible

    // ---- conv2 p1 (waves 0-7, continue accumulating in c0)
    if (w < 8) {
        __builtin_amdgcn_s_setprio(1);
#pragma unroll 2
        for (int i = 0; i < 16; i++) {
            f16x8 bh2 = *(const f16x8*)(b2h + (size_t)(16 + i) * 4096);
            f16x8 bl2 = *(const f16x8*)(b2l + (size_t)(16 + i) * 4096);
            f16x8 gh[4], gl[4];
#pragma unroll
            for (int m = 0; m < 4; m++) {
                int go = (m * 32 + arow) * 264 + i * 16 + acol;
                gh[m] = *(const f16x8*)&GH[go];
                gl[m] = *(const f16x8*)&GL[go];
            }
#pragma unroll
            for (int m = 0; m < 4; m++)
                c0[m] = __builtin_amdgcn_mfma_f32_32x32x16_f16(gh[m], bh2, c0[m], 0, 0, 0);
#pragma unroll
            for (int m = 0; m < 4; m++)
                c0[m] = __builtin_amdgcn_mfma_f32_32x32x16_f16(gh[m], bl2, c0[m], 0, 0, 0);
#pragma unroll
            for (int m = 0; m < 4; m++)
                c0[m] = __builtin_amdgcn_mfma_f32_32x32x16_f16(gl[m], bh2, c0[m], 0, 0, 0);
        }
        __builtin_amdgcn_s_setprio(0);
    }
    __syncthreads();                                   // B6: all G reads done

    // ---- SOUT (waves 0-7 hold conv2 output; overlay on G)
    if (w < 8) {
        int oc = w * 32 + (lane & 31);
#pragma unroll
        for (int m = 0; m < 4; m++)
#pragma unroll
            for (int r = 0; r < 16; r++) {
                int trow = m * 32 + thalf + ((r >> 2) << 3) + (r & 3);
                SOUT[trow * 260 + oc] = c0[m][r];
            }
    }
    __syncthreads();                                   // B7
    {
        int t = tid & 127, cg = tid >> 7;              // 8 ch-groups
        float mk = mask[bT + t0 + t];
        float s = 0.f, s2 = 0.f;
#pragma unroll
        for (int i = 0; i < 32; i++) {
            int c = cg * 32 + i;
            size_t adr = xoff + (size_t)c * T + t0 + t;
            float val = (xin[adr] + SOUT[t * 260 + c] + b2[c]) * mk;
            xout[adr] = val;
            s += val; s2 += val * val;
        }
        rs[tid] = s; rs2[tid] = s2;
    }
    __syncthreads();                                   // B8
    if (tid < 128) {
        float ss = 0.f, ss2 = 0.f;
#pragma unroll
        for (int k = 0; k < 8; k++) {
            ss += rs[k * 128 + tid]; ss2 += rs2[k * 128 + tid];
        }
        float m = ss * (1.0f / 256.0f);
        float var = ss2 * (1.0f / 256.0f) - m * m;
        MMo[bT + t0 + tid] = m;
        IVo[bT + t0 + tid] = 1.0f / sqrtf(var + 1e-5f);
    }
}

// ---------------- postnet fused sub-block: M=32, 1024 thr / 16 waves --------
__global__ __launch_bounds__(1024, 4) void k_sub16(
    const float* __restrict__ xin, float* __restrict__ xout,
    const float* __restrict__ MMi, const float* __restrict__ IVi,
    const float* __restrict__ lng, const float* __restrict__ lnb,
    const u16* __restrict__ B1H, const u16* __restrict__ B1L,
    const float* __restrict__ b1,
    const u16* __restrict__ B2H, const u16* __restrict__ B2L,
    const float* __restrict__ b2, const float* __restrict__ mask,
    float* __restrict__ MMo, float* __restrict__ IVo, int T) {
    __shared__ __align__(16) char smem[76800];
    u16* LH = (u16*)smem;                     // [34][264] u16 = 17952 B
    u16* LL = (u16*)(smem + 17952);           // 17952  (total 35904)
    u16* GH = (u16*)smem;                     // overlay [32][536] = 34304 B
    u16* GL = (u16*)(smem + 34304);           // 34304  (total 68608)
    float* SOUT  = (float*)smem;              // overlay [32][260] f32 = 33280
    float* SOUT2 = (float*)(smem + 34304);    // overlay on GL, 33280
    float* rs  = (float*)(smem + 68608);      // 1024 f32
    float* rs2 = (float*)(smem + 72704);      // 1024 f32

    const int tid = threadIdx.x;
    const int b = blockIdx.y, t0 = blockIdx.x * 32;
    const size_t xoff = (size_t)b * 256 * T;
    const size_t bT = (size_t)b * T;

    // ---- stage
    {
        int jj = tid & 31;
        int cg = tid >> 5;                    // 0..31
        int t = t0 - 2 + jj;
        bool ok = (t >= 0);
        float m = ok ? MMi[bT + t] : 0.f;
        float v = ok ? IVi[bT + t] : 0.f;
#pragma unroll
        for (int i = 0; i < 8; i++) {
            int c = cg + i * 32;
            float xv = ok ? xin[xoff + (size_t)c * T + t] : 0.f;
            float ln = ok ? ((xv - m) * v * lng[c] + lnb[c]) : 0.f;
            u16 h, l; split_f16(ln, h, l);
            LH[jj * 264 + c] = h; LL[jj * 264 + c] = l;
        }
        if (tid < 512) {
            int j2 = 32 + (tid >> 8);
            int c2 = tid & 255;
            int t2 = t0 + 30 + (tid >> 8);
            float ln2 = (xin[xoff + (size_t)c2 * T + t2] - MMi[bT + t2]) *
                        IVi[bT + t2] * lng[c2] + lnb[c2];
            u16 h2, l2; split_f16(ln2, h2, l2);
            LH[j2 * 264 + c2] = h2; LL[j2 * 264 + c2] = l2;
        }
    }
    __syncthreads();                                   // B1

    const int lane = tid & 63;
    const int w = tid >> 6;                            // 0..15
    const int arow = lane & 31;
    const int acol = (lane >> 5) << 3;
    const int thalf = (lane >> 5) << 2;
    const int oc_l = w * 32 + (lane & 31);             // 0..511
    const u16* b1h = B1H + (size_t)w * 512 + (size_t)lane * 8;   // nt = w
    const u16* b1l = B1L + (size_t)w * 512 + (size_t)lane * 8;

    // ---- conv1: one n-tile per wave (144 MFMA)
    f32x16 cc;
#pragma unroll
    for (int r = 0; r < 16; r++) cc[r] = 0.f;
    __builtin_amdgcn_s_setprio(1);
#pragma unroll 4
    for (int kk = 0; kk < 48; kk++) {
        int k3 = kk >> 4, kb = kk & 15;
        int ao = (arow + k3) * 264 + kb * 16 + acol;
        f16x8 ah = *(const f16x8*)&LH[ao];
        f16x8 al = *(const f16x8*)&LL[ao];
        f16x8 bh = *(const f16x8*)(b1h + (size_t)kk * 8192);
        f16x8 bl = *(const f16x8*)(b1l + (size_t)kk * 8192);
        cc = __builtin_amdgcn_mfma_f32_32x32x16_f16(ah, bh, cc, 0, 0, 0);
        cc = __builtin_amdgcn_mfma_f32_32x32x16_f16(ah, bl, cc, 0, 0, 0);
        cc = __builtin_amdgcn_mfma_f32_32x32x16_f16(al, bh, cc, 0, 0, 0);
    }
    __builtin_amdgcn_s_setprio(0);
    __syncthreads();                                   // B2: LH/LL dead

    // ---- pack: ALL 16 waves write their 32 oc columns of the full-K G
    {
        float bb = b1[oc_l];
#pragma unroll
        for (int r = 0; r < 16; r++) {
            int trow = thalf + ((r >> 2) << 3) + (r & 3);
            gelu_pack(cc[r], bb, GH, GL, trow * 536 + oc_l);
        }
    }
    __syncthreads();                                   // B3: G visible

    // ---- conv2: all 16 waves.  wave w: n-tile w&7, ic-half w>>3.
    const int nt2 = w & 7;
    const int ih = w >> 3;
    const u16* b2h = B2H + (size_t)nt2 * 512 + (size_t)lane * 8;
    const u16* b2l = B2L + (size_t)nt2 * 512 + (size_t)lane * 8;
#pragma unroll
    for (int r = 0; r < 16; r++) cc[r] = 0.f;
    __builtin_amdgcn_s_setprio(1);
#pragma unroll 4
    for (int i = 0; i < 16; i++) {
        int ii = ih * 16 + i;
        int go = arow * 536 + ii * 16 + acol;
        f16x8 gh = *(const f16x8*)&GH[go];
        f16x8 gl = *(const f16x8*)&GL[go];
        f16x8 bh2 = *(const f16x8*)(b2h + (size_t)ii * 4096);
        f16x8 bl2 = *(const f16x8*)(b2l + (size_t)ii * 4096);
        cc = __builtin_amdgcn_mfma_f32_32x32x16_f16(gh, bh2, cc, 0, 0, 0);
        cc = __builtin_amdgcn_mfma_f32_32x32x16_f16(gh, bl2, cc, 0, 0, 0);
        cc = __builtin_amdgcn_mfma_f32_32x32x16_f16(gl, bh2, cc, 0, 0, 0);
    }
    __builtin_amdgcn_s_setprio(0);
    __syncthreads();                                   // B4: all G reads done

    // ---- SOUT dual-buffer write (no RMW, no extra barrier)
    if (w < 8) {
#pragma unroll
        for (int r = 0; r < 16; r++) {
            int trow = thalf + ((r >> 2) << 3) + (r & 3);
            SOUT[trow * 260 + oc_l] = cc[r];
        }
    } else {
        int oc2 = nt2 * 32 + (lane & 31);
#pragma unroll
        for (int r = 0; r < 16; r++) {
            int trow = thalf + ((r >> 2) << 3) + (r & 3);
            SOUT2[trow * 260 + oc2] = cc[r];
        }
    }
    __syncthreads();                                   // B5
    {
        int t = tid & 31, cg = tid >> 5;               // cg 0..31
        float mk = mask[bT + t0 + t];
        float s = 0.f, s2 = 0.f;
#pragma unroll
        for (int i = 0; i < 8; i++) {
            int c = cg * 8 + i;
            size_t adr = xoff + (size_t)c * T + t0 + t;
            float val = (xin[adr] + (SOUT[t * 260 + c] + SOUT2[t * 260 + c]) +
                         b2[c]) * mk;
            xout[adr] = val;
            s += val; s2 += val * val;
        }
        rs[tid] = s; rs2[tid] = s2;
    }
    __syncthreads();                                   // B6
    if (tid < 32) {
        float ss = 0.f, ss2 = 0.f;
#pragma unroll
        for (int k = 0; k < 32; k++) {
            ss += rs[k * 32 + tid]; ss2 += rs2[k * 32 + tid];
        }
        float m = ss * (1.0f / 256.0f);
        float var = ss2 * (1.0f / 256.0f) - m * m;
        MMo[bT + t0 + tid] = m;
        IVo[bT + t0 + tid] = 1.0f / sqrtf(var + 1e-5f);
    }
}

// ---------------- final LN*mask + causal conv via MFMA (templated M) --------
template <int M>
__global__ __launch_bounds__(512, (M == 32 ? 8 : 4)) void k_lnc(
    const float* __restrict__ xin, float* __restrict__ xout,
    const float* __restrict__ MM, const float* __restrict__ IV,
    const float* __restrict__ lg, const float* __restrict__ lb,
    const u16* __restrict__ BH, const u16* __restrict__ BL,
    const float* __restrict__ bias, const float* __restrict__ mask, int T) {
    constexpr int MT = M / 32;
    constexpr int SH = (M + 2) * 264 * 2;
    constexpr int CG = 512 / M;
    constexpr int CPT = 256 / CG;
    __shared__ __align__(16) char smem[2 * SH];
    u16* LH = (u16*)smem;
    u16* LL = (u16*)(smem + SH);
    float* SOUT = (float*)smem;               // overlay

    const int tid = threadIdx.x;
    const int b = blockIdx.y, t0 = blockIdx.x * M;
    const size_t xoff = (size_t)b * 256 * T;
    const size_t bT = (size_t)b * T;

    {   // stage: (LN(x)*mask) hi/lo
        int jj = tid & (M - 1);
        int cg = tid / M;
        int t = t0 - 2 + jj;
        bool ok = (t >= 0);
        float m = ok ? MM[bT + t] : 0.f;
        float v = ok ? IV[bT + t] : 0.f;
        float mk = ok ? mask[bT + t] : 0.f;
#pragma unroll
        for (int i = 0; i < CPT; i++) {
            int c = cg + i * CG;
            float xv = ok ? xin[xoff + (size_t)c * T + t] : 0.f;
            float ln = ok ? ((xv - m) * v * lg[c] + lb[c]) * mk : 0.f;
            u16 h, l; split_f16(ln, h, l);
            LH[jj * 264 + c] = h; LL[jj * 264 + c] = l;
        }
        int j2 = M + (tid >> 8);
        int c2 = tid & 255;
        int t2 = t0 + (M - 2) + (tid >> 8);
        float ln2 = ((xin[xoff + (size_t)c2 * T + t2] - MM[bT + t2]) *
                     IV[bT + t2] * lg[c2] + lb[c2]) * mask[bT + t2];
        u16 h2, l2; split_f16(ln2, h2, l2);
        LH[j2 * 264 + c2] = h2; LL[j2 * 264 + c2] = l2;
    }
    __syncthreads();

    const int lane = tid & 63;
    const int w = tid >> 6;
    const int arow = lane & 31;
    const int acol = (lane >> 5) << 3;
    const int thalf = (lane >> 5) << 2;
    const u16* bph = BH + (size_t)w * 512 + (size_t)lane * 8;
    const u16* bpl = BL + (size_t)w * 512 + (size_t)lane * 8;

    f32x16 aH[MT], aM[MT];
#pragma unroll
    for (int m = 0; m < MT; m++)
#pragma unroll
        for (int r = 0; r < 16; r++) { aH[m][r] = 0.f; aM[m][r] = 0.f; }
    __builtin_amdgcn_s_setprio(1);
#pragma unroll 2
    for (int kk = 0; kk < 48; kk++) {
        int k3 = kk >> 4, kb = kk & 15;
        f16x8 bh = *(const f16x8*)(bph + (size_t)kk * 4096);
        f16x8 bl = *(const f16x8*)(bpl + (size_t)kk * 4096);
        f16x8 ah[MT], al[MT];
#pragma unroll
        for (int m = 0; m < MT; m++) {
            int ao = (m * 32 + arow + k3) * 264 + kb * 16 + acol;
            ah[m] = *(const f16x8*)&LH[ao];
            al[m] = *(const f16x8*)&LL[ao];
        }
#pragma unroll
        for (int m = 0; m < MT; m++)
            aH[m] = __builtin_amdgcn_mfma_f32_32x32x16_f16(ah[m], bh, aH[m], 0, 0, 0);
#pragma unroll
        for (int m = 0; m < MT; m++)
            aM[m] = __builtin_amdgcn_mfma_f32_32x32x16_f16(ah[m], bl, aM[m], 0, 0, 0);
#pragma unroll
        for (int m = 0; m < MT; m++)
            aM[m] = __builtin_amdgcn_mfma_f32_32x32x16_f16(al[m], bh, aM[m], 0, 0, 0);
    }
    __builtin_amdgcn_s_setprio(0);
    __syncthreads();  // all LH/LL reads done before SOUT overlay
    {
        int oc = w * 32 + (lane & 31);
#pragma unroll
        for (int m = 0; m < MT; m++)
#pragma unroll
            for (int r = 0; r < 16; r++) {
                int trow = m * 32 + thalf + ((r >> 2) << 3) + (r & 3);
                SOUT[trow * 260 + oc] = aH[m][r] + aM[m][r];
            }
    }
    __syncthreads();
    {
        int t = tid & (M - 1), cg = tid / M;
        float mk = mask[bT + t0 + t];
#pragma unroll
        for (int i = 0; i < CPT; i++) {
            int c = cg * CPT + i;
            xout[xoff + (size_t)c * T + t0 + t] =
                (SOUT[t * 260 + c] + bias[c]) * mk;
        }
    }
}

// ---------------- group-by-segments (scatter mean) --------------------------
__global__ __launch_bounds__(256) void k_counts(const int* __restrict__ m2p,
                                                int* __restrict__ cnt) {
    __shared__ int c[512];
    int b = blockIdx.x;
    for (int i = threadIdx.x; i < 512; i += 256) c[i] = 0;
    __syncthreads();
    for (int t = threadIdx.x; t < 2048; t += 256) {
        int p = m2p[b * 2048 + t];
        if (p >= 1 && p <= 512) atomicAdd(&c[p - 1], 1);
    }
    __syncthreads();
    for (int i = threadIdx.x; i < 512; i += 256) cnt[b * 512 + i] = c[i];
}

__global__ __launch_bounds__(256) void k_scatter(const float* __restrict__ h,
                                                 const int* __restrict__ m2p,
                                                 float* __restrict__ g) {
    extern __shared__ float sm[];
    float* HT = sm;
    int* ph = (int*)(sm + 256 * 65);
    int b = blockIdx.y, t0 = blockIdx.x * 64;
    if (threadIdx.x < 64) ph[threadIdx.x] = m2p[b * 2048 + t0 + threadIdx.x];
    for (int i = threadIdx.x; i < 256 * 64; i += 256) {
        int c = i >> 6, j = i & 63;
        HT[c * 65 + j] = h[((size_t)b * 256 + c) * 2048 + t0 + j];
    }
    __syncthreads();
    int c = threadIdx.x;
    float run = 0.f;
    int cur = ph[0];
    for (int j = 0; j < 64; j++) {
        int p = ph[j];
        if (p != cur) {
            if (cur >= 1 && cur <= 512)
                atomicAdd(&g[((size_t)b * 256 + c) * 512 + cur - 1], run);
            run = 0.f;
            cur = p;
        }
        run += HT[c * 65 + j];
    }
    if (cur >= 1 && cur <= 512)
        atomicAdd(&g[((size_t)b * 256 + c) * 512 + cur - 1], run);
}

__global__ __launch_bounds__(512) void k_postprep(float* __restrict__ g,
                                                  const int* __restrict__ cnt,
                                                  float* __restrict__ MM,
                                                  float* __restrict__ IV) {
    int b = blockIdx.x, l = threadIdx.x;
    int c1 = cnt[b * 512 + l];
    if (c1 < 1) c1 = 1;
    float rc = 1.0f / (float)c1;
    float s = 0.f, s2 = 0.f;
    for (int c = 0; c < 256; c++) {
        size_t idx = ((size_t)b * 256 + c) * 512 + l;
        float v = g[idx] * rc;
        g[idx] = v;
        s += v; s2 += v * v;
    }
    float m = s * (1.0f / 256.0f);
    float var = s2 * (1.0f / 256.0f) - m * m;
    MM[(size_t)b * 512 + l] = m;
    IV[(size_t)b * 512 + l] = 1.0f / sqrtf(var + 1e-5f);
}

// ---------------- VQ (lane-pair K-split) ------------------------------------
__global__ __launch_bounds__(256) void k_vq(const float* __restrict__ z,
                                            const float* __restrict__ cb,
                                            int* __restrict__ idxout,
                                            float* __restrict__ out,
                                            float* __restrict__ lossacc) {
    int n2 = blockIdx.x * 256 + threadIdx.x;   // 16384 total (grid 64)
    int n = n2 >> 1;                           // (b,l) work item
    int half = n2 & 1;                         // codebook half
    int b = n >> 9, l = n & 511;
    float zr[64];
#pragma unroll
    for (int c = 0; c < 64; c++) zr[c] = z[((size_t)b * 64 + c) * 512 + l];
    float best = 3.4e38f;
    int bi = 0;
    int k0 = half * 64;
    for (int k = k0; k < k0 + 64; k++) {
        const float* cr = cb + k * 64;
        float d = 0.f;
#pragma unroll
        for (int c = 0; c < 64; c++) {
            float t = zr[c] - cr[c];
            d = fmaf(t, t, d);
        }
        if (d < best) { best = d; bi = k; }
    }
    // combine across the lane pair (first-min semantics: lower k wins ties)
    float bestO = __shfl_xor(best, 1);
    int biO = __shfl_xor(bi, 1);
    if (bestO < best || (bestO == best && biO < bi)) { best = bestO; bi = biO; }
    if (half == 0) {
        idxout[n] = bi;
        out[OUT_IDX_OFF + n] = (float)bi;
        atomicAdd(lossacc, best);
    }
}

__global__ void k_loss(const float* __restrict__ acc, float* __restrict__ out) {
    if (threadIdx.x == 0 && blockIdx.x == 0)
        out[OUT_LOSS_OFF] = 0.25f * acc[0] * (1.0f / 524288.0f);
}

// ---------------- proj_out --------------------------------------------------
__global__ __launch_bounds__(256) void k_projout(const float* __restrict__ cb,
                                                 const int* __restrict__ idx,
                                                 const float* __restrict__ wt,
                                                 const float* __restrict__ bias,
                                                 float* __restrict__ out) {
    __shared__ float Q[64 * 64];
    __shared__ int ids[64];
    int b = blockIdx.y, l0 = blockIdx.x * 64;
    if (threadIdx.x < 64) ids[threadIdx.x] = idx[b * 512 + l0 + threadIdx.x];
    __syncthreads();
    for (int i = threadIdx.x; i < 4096; i += 256) {
        int c = i >> 6, l = i & 63;
        Q[c * 64 + l] = cb[ids[l] * 64 + c];
    }
    __syncthreads();
    int tl = threadIdx.x & 63;
    int g = __builtin_amdgcn_readfirstlane((int)(threadIdx.x >> 6));
    float acc[64];
#pragma unroll
    for (int o = 0; o < 64; o++) acc[o] = 0.f;
    for (int i = 0; i < 64; i++) {
        float xv = Q[i * 64 + tl];
        const float* wr = wt + i * 256 + g * 64;
#pragma unroll
        for (int o = 0; o < 64; o++) acc[o] = fmaf(wr[o], xv, acc[o]);
    }
#pragma unroll
    for (int o = 0; o < 64; o++) {
        int oc = g * 64 + o;
        out[(size_t)b * 131072 + (size_t)oc * 512 + l0 + tl] = acc[o] + bias[oc];
    }
}

// ---------------------------------------------------------------------------
extern "C" void kernel_launch(void* const* d_in, const int* in_sizes, int n_in,
                              void* d_out, int out_size, void* d_ws, size_t ws_size,
                              hipStream_t stream) {
    (void)in_sizes; (void)n_in; (void)out_size; (void)ws_size;
    const float* x          = (const float*)d_in[0];
    const float* in_np      = (const float*)d_in[1];
    const int*   mel2ph     = (const int*)d_in[2];
    const float* ph_np      = (const float*)d_in[3];
    const float* conv_in_w  = (const float*)d_in[4];
    const float* conv_in_b  = (const float*)d_in[5];
    const float* e_ln_g = (const float*)d_in[6];
    const float* e_ln_b = (const float*)d_in[7];
    const float* e_w1   = (const float*)d_in[8];
    const float* e_b1   = (const float*)d_in[9];
    const float* e_w2   = (const float*)d_in[10];
    const float* e_b2   = (const float*)d_in[11];
    const float* e_lg   = (const float*)d_in[12];
    const float* e_lb   = (const float*)d_in[13];
    const float* e_pw   = (const float*)d_in[14];
    const float* e_pb   = (const float*)d_in[15];
    const float* p_ln_g = (const float*)d_in[16];
    const float* p_ln_b = (const float*)d_in[17];
    const float* p_w1   = (const float*)d_in[18];
    const float* p_b1   = (const float*)d_in[19];
    const float* p_w2   = (const float*)d_in[20];
    const float* p_b2   = (const float*)d_in[21];
    const float* p_lg   = (const float*)d_in[22];
    const float* p_lb   = (const float*)d_in[23];
    const float* p_pw   = (const float*)d_in[24];
    const float* p_pb   = (const float*)d_in[25];
    const float* proj_in_w  = (const float*)d_in[26];
    const float* proj_in_b  = (const float*)d_in[27];
    const float* proj_out_w = (const float*)d_in[28];
    const float* proj_out_b = (const float*)d_in[29];
    const float* codebook   = (const float*)d_in[30];
    float* out = (float*)d_out;

    float* ws = (float*)d_ws;
    float* A      = ws;                        // 8388608
    float* Bb     = A + 8388608;               // 8388608
    float* CINT   = Bb + 8388608;              // 20480
    float* PINT   = CINT + 20480;              // 16384
    float* POUTT  = PINT + 16384;              // 16384
    float* Z      = POUTT + 16384;             // 524288
    float* MM0    = Z + 524288;                // 32768
    float* IV0    = MM0 + 32768;               // 32768
    float* MM1    = IV0 + 32768;               // 32768
    float* IV1    = MM1 + 32768;               // 32768
    int*   CNT    = (int*)(IV1 + 32768);       // 8192
    int*   IDX    = CNT + 8192;                // 8192
    float* LOSS   = (float*)(IDX + 8192);      // 64 (aligned pad)
    u16*   BH1E   = (u16*)(LOSS + 64);         // 3932160 each
    u16*   BL1E   = BH1E + 3932160;
    u16*   BH1P   = BL1E + 3932160;
    u16*   BL1P   = BH1P + 3932160;
    u16*   BH2E   = BL1P + 3932160;            // 1310720 each
    u16*   BL2E   = BH2E + 1310720;
    u16*   BH2P   = BL2E + 1310720;
    u16*   BL2P   = BH2P + 1310720;
    u16*   PH_E   = BL2P + 1310720;            // 196608 each
    u16*   PL_E   = PH_E + 196608;
    u16*   PH_P   = PL_E + 196608;
    u16*   PL_P   = PH_P + 196608;

    // weight prep (ws re-poisoned every call -> recompute)
    k_t_w1mf<<<dim3(4096), dim3(256), 0, stream>>>(e_w1, BH1E, BL1E, 10);
    k_t_w1mf<<<dim3(4096), dim3(256), 0, stream>>>(p_w1, BH1P, BL1P, 10);
    k_t_w2mf<<<dim3(2048), dim3(256), 0, stream>>>(e_w2, BH2E, BL2E, 10);
    k_t_w2mf<<<dim3(2048), dim3(256), 0, stream>>>(p_w2, BH2P, BL2P, 10);
    k_t_wpmf<<<dim3(768),  dim3(256), 0, stream>>>(e_pw, PH_E, PL_E);
    k_t_wpmf<<<dim3(768),  dim3(256), 0, stream>>>(p_pw, PH_P, PL_P);
    k_t_mat  <<<dim3(80),  dim3(256), 0, stream>>>(conv_in_w, CINT, 1, 256, 80);
    k_t_mat  <<<dim3(64),  dim3(256), 0, stream>>>(proj_in_w, PINT, 1, 64, 256);
    k_t_mat  <<<dim3(64),  dim3(256), 0, stream>>>(proj_out_w, POUTT, 1, 256, 64);

    const size_t sm_scat = 256 * 65 * sizeof(float) + 64 * sizeof(int);

    // ---- conv_in + mask -> A (+ LN stats for encoder layer 0)
    k_pw<80, 256, 64, true><<<dim3(32, 16), dim3(256), 80 * 64 * 4, stream>>>(
        x, CINT, conv_in_b, in_np, A, MM0, IV0, 2048);

    // ---- encoder: 10 M=128 sub-blocks, ping-pong A<->B and MM0/1
    float* cur = A;
    float* nxt = Bb;
    for (int s = 0; s < 10; s++) {
        float* mi = (s & 1) ? MM1 : MM0;
        float* vi = (s & 1) ? IV1 : IV0;
        float* mo = (s & 1) ? MM0 : MM1;
        float* vo = (s & 1) ? IV0 : IV1;
        k_sub128<<<dim3(16, 16), dim3(1024), 0, stream>>>(
            cur, nxt, mi, vi, e_ln_g + s * 256, e_ln_b + s * 256,
            BH1E + (size_t)s * 393216, BL1E + (size_t)s * 393216, e_b1 + s * 512,
            BH2E + (size_t)s * 131072, BL2E + (size_t)s * 131072, e_b2 + s * 256,
            in_np, mo, vo, 2048);
        float* t = cur; cur = nxt; nxt = t;
    }
    // final stats in MM0/IV0 (s=9 odd -> wrote MM0)
    k_lnc<64><<<dim3(32, 16), dim3(512), 0, stream>>>(
        cur, nxt, MM0, IV0, e_lg, e_lb, PH_E, PL_E, e_pb, in_np, 2048);

    // ---- group-by-segs: B (T=2048) -> A (compact [16,256,512])
    hipMemsetAsync(A, 0, (size_t)2097152 * 4, stream);
    hipMemsetAsync(LOSS, 0, 4, stream);
    k_counts<<<dim3(16), dim3(256), 0, stream>>>(mel2ph, CNT);
    k_scatter<<<dim3(32, 16), dim3(256), sm_scat, stream>>>(Bb, mel2ph, A);
    k_postprep<<<dim3(16), dim3(512), 0, stream>>>(A, CNT, MM0, IV0);

    // ---- postnet: 10 fused sub-blocks on T=512 (M=32, 16 waves)
    cur = A; nxt = Bb;
    for (int s = 0; s < 10; s++) {
        float* mi = (s & 1) ? MM1 : MM0;
        float* vi = (s & 1) ? IV1 : IV0;
        float* mo = (s & 1) ? MM0 : MM1;
        float* vo = (s & 1) ? IV0 : IV1;
        k_sub16<<<dim3(16, 16), dim3(1024), 0, stream>>>(
            cur, nxt, mi, vi, p_ln_g + s * 256, p_ln_b + s * 256,
            BH1P + (size_t)s * 393216, BL1P + (size_t)s * 393216, p_b1 + s * 512,
            BH2P + (size_t)s * 131072, BL2P + (size_t)s * 131072, p_b2 + s * 256,
            ph_np, mo, vo, 512);
        float* t = cur; cur = nxt; nxt = t;
    }
    k_lnc<32><<<dim3(16, 16), dim3(512), 0, stream>>>(
        cur, nxt, MM0, IV0, p_lg, p_lb, PH_P, PL_P, p_pb, ph_np, 512);

    // ---- proj_in: B -> Z [16,64,512]
    k_pw<256, 64, 16, false><<<dim3(8, 16), dim3(256), 256 * 64 * 4, stream>>>(
        Bb, PINT, proj_in_b, nullptr, Z, nullptr, nullptr, 512);

    // ---- VQ + loss + proj_out
    k_vq<<<dim3(64), dim3(256), 0, stream>>>(Z, codebook, IDX, out, LOSS);
    k_loss<<<dim3(1), dim3(64), 0, stream>>>(LOSS, out);
    k_projout<<<dim3(8, 16), dim3(256), 0, stream>>>(codebook, IDX, POUTT,
                                                     proj_out_b, out);
}

// Round 11
// 2006.041 us; speedup vs baseline: 1.0580x; 1.0401x over previous
//
#include <hip/hip_runtime.h>
#include <hip/hip_bf16.h>

// ---------------------------------------------------------------------------
// StyleEncoder pipeline for MI355X (gfx950).  R21:
//  - Encoder: R17's k_sub<64> (best measured 119.6us; M=128/paired/2-block
//    variants all pinned at ~120-124us, 38% MfmaUtil -> per-wave latency
//    bound at 4 waves/SIMD; structural local optimum).
//  - Weight prep: 9 launches fused to 4 (w1 e+p, w2 e+p, wpmf e+p, mat x3).
//    Same per-element math -> bit-identical outputs; saves ~5 launch gaps.
//  - Postnet k_sub16 (dual SOUT), k_lnc, k_vq lane-pair: R17 verbatim.
// All inputs fp32; d_out fp32: out @0, vq_loss @2097152, idx @2097153.
// ---------------------------------------------------------------------------

typedef unsigned short u16;
typedef unsigned int u32;
typedef __attribute__((ext_vector_type(8))) _Float16 f16x8;
typedef __attribute__((ext_vector_type(16))) float f32x16;

#define OUT_LOSS_OFF 2097152
#define OUT_IDX_OFF  2097153

__device__ __forceinline__ void split_f16(float x, u16& h, u16& l) {
    union { _Float16 f; u16 u; } a, b;
    a.f = (_Float16)x;              // RNE f32->f16
    float hf = (float)a.f;
    b.f = (_Float16)(x - hf);       // residual, RNE to f16
    h = a.u; l = b.u;
}

__device__ __forceinline__ void gelu_pack(float v, float bb, u16* GH, u16* GL,
                                          int off) {
    const float ks = 0.5773502691896258f;
    float y = (v + bb) * ks;
    float ge = 0.5f * y * (1.0f + erff(y * 0.7071067811865476f));
    u16 h, l; split_f16(ge, h, l);
    GH[off] = h; GL[off] = l;
}

// ---------------- fused weight transposes ------------------------------------
// W1 (enc+post) -> B-fragment layout, split hi/lo f16.
// idx = ((((s*3+k3)*16+kb)*16+nt)*64+L)*8+j ; val = w1[s][oc][c][k3]
__global__ __launch_bounds__(256) void k_t_w1mf2(
    const float* __restrict__ wE, const float* __restrict__ wP,
    u16* __restrict__ BHE, u16* __restrict__ BLE,
    u16* __restrict__ BHP, u16* __restrict__ BLP) {
    const size_t N = (size_t)10 * 3 * 16 * 16 * 64 * 8;   // 3,932,160
    for (size_t ii = (size_t)blockIdx.x * 256 + threadIdx.x; ii < 2 * N;
         ii += (size_t)gridDim.x * 256) {
        int which = ii >= N;
        size_t i = which ? (ii - N) : ii;
        const float* w = which ? wP : wE;
        u16* BH = which ? BHP : BHE;
        u16* BL = which ? BLP : BLE;
        int j = (int)(i & 7); size_t r = i >> 3;
        int L = (int)(r & 63); r >>= 6;
        int nt = (int)(r & 15); r >>= 4;
        int kb = (int)(r & 15); r >>= 4;
        int k3 = (int)(r % 3); int s = (int)(r / 3);
        int oc = nt * 32 + (L & 31);
        int c = kb * 16 + ((L >> 5) << 3) + j;
        float v = w[(((size_t)s * 512 + oc) * 256 + c) * 3 + k3];
        u16 h, l; split_f16(v, h, l);
        BH[i] = h; BL[i] = l;
    }
}

// W2 (enc+post). idx = (((s*32+kb)*8+nt)*64+L)*8+j
__global__ __launch_bounds__(256) void k_t_w2mf2(
    const float* __restrict__ wE, const float* __restrict__ wP,
    u16* __restrict__ BHE, u16* __restrict__ BLE,
    u16* __restrict__ BHP, u16* __restrict__ BLP) {
    const size_t N = (size_t)10 * 32 * 8 * 64 * 8;        // 1,310,720
    for (size_t ii = (size_t)blockIdx.x * 256 + threadIdx.x; ii < 2 * N;
         ii += (size_t)gridDim.x * 256) {
        int which = ii >= N;
        size_t i = which ? (ii - N) : ii;
        const float* w = which ? wP : wE;
        u16* BH = which ? BHP : BHE;
        u16* BL = which ? BLP : BLE;
        int j = (int)(i & 7);
        int L = (int)((i >> 3) & 63);
        int nt = (int)((i >> 9) & 7);
        int kb = (int)((i >> 12) & 31);
        int s = (int)(i >> 17);
        int oc = nt * 32 + (L & 31);
        int ic = kb * 16 + ((L >> 5) << 3) + j;
        float v = w[((size_t)s * 256 + oc) * 512 + ic];
        u16 h, l; split_f16(v, h, l);
        BH[i] = h; BL[i] = l;
    }
}

// post-conv W (enc+post), [256 oc][256 c][3 k3] -> B-frag (O=256, K=768).
__global__ __launch_bounds__(256) void k_t_wpmf2(
    const float* __restrict__ wE, const float* __restrict__ wP,
    u16* __restrict__ BHE, u16* __restrict__ BLE,
    u16* __restrict__ BHP, u16* __restrict__ BLP) {
    const int N = 196608;
    for (int ii = blockIdx.x * 256 + threadIdx.x; ii < 2 * N;
         ii += gridDim.x * 256) {
        int which = ii >= N;
        int i = which ? (ii - N) : ii;
        const float* w = which ? wP : wE;
        u16* BH = which ? BHP : BHE;
        u16* BL = which ? BLP : BLE;
        int j = i & 7;
        int L = (i >> 3) & 63;
        int nt = (i >> 9) & 7;
        int kb = (i >> 12) & 15;
        int k3 = i >> 16;
        int oc = nt * 32 + (L & 31);
        int c = kb * 16 + ((L >> 5) << 3) + j;
        float v = w[((size_t)oc * 256 + c) * 3 + k3];
        u16 h, l; split_f16(v, h, l);
        BH[i] = h; BL[i] = l;
    }
}

// three small pointwise-weight transposes in one launch.
// seg0: conv_in_w [256][80] -> CINT [80][256]
// seg1: proj_in_w [64][256] -> PINT [256][64]
// seg2: proj_out_w [256][64] -> POUTT [64][256]
__global__ __launch_bounds__(256) void k_t_mat3(
    const float* __restrict__ w0, const float* __restrict__ w1,
    const float* __restrict__ w2, float* __restrict__ t0,
    float* __restrict__ t1, float* __restrict__ t2) {
    const int N0 = 20480, N1 = 16384, N2 = 16384;
    for (int i = blockIdx.x * 256 + threadIdx.x; i < N0 + N1 + N2;
         i += gridDim.x * 256) {
        if (i < N0) {
            int ci = i % 80, o = i / 80;
            t0[(size_t)ci * 256 + o] = w0[i];
        } else if (i < N0 + N1) {
            int k = i - N0;
            int ci = k % 256, o = k / 256;
            t1[(size_t)ci * 64 + o] = w1[k];
        } else {
            int k = i - N0 - N1;
            int ci = k % 64, o = k / 64;
            t2[(size_t)ci * 256 + o] = w2[k];
        }
    }
}

// ---------------- pointwise conv (+ optional column stats) ------------------
template <int CIN, int COUT, int CHUNK, bool STATS>
__global__ __launch_bounds__(256) void k_pw(const float* __restrict__ x,
                                            const float* __restrict__ wt,
                                            const float* __restrict__ bias,
                                            const float* __restrict__ mask,
                                            float* __restrict__ y,
                                            float* __restrict__ MM,
                                            float* __restrict__ IV, int T) {
    extern __shared__ float X[];
    constexpr int NG = COUT / CHUNK;
    __shared__ float rs[64 * NG], rs2[64 * NG];
    const int b = blockIdx.y, t0 = blockIdx.x * 64;
    for (int i = threadIdx.x; i < CIN * 64; i += 256) {
        int ci = i >> 6, j = i & 63;
        X[i] = x[((size_t)b * CIN + ci) * T + t0 + j];
    }
    __syncthreads();
    const int tl = threadIdx.x & 63;
    const int g = __builtin_amdgcn_readfirstlane((int)(threadIdx.x >> 6));
    float acc[CHUNK];
#pragma unroll
    for (int o = 0; o < CHUNK; o++) acc[o] = 0.f;
    for (int i = 0; i < CIN; i++) {
        float xv = X[i * 64 + tl];
        const float* wr = wt + (size_t)i * COUT + g * CHUNK;
#pragma unroll
        for (int o = 0; o < CHUNK; o++) acc[o] = fmaf(wr[o], xv, acc[o]);
    }
    float mk = mask ? mask[(size_t)b * T + t0 + tl] : 1.0f;
    float s = 0.f, s2 = 0.f;
#pragma unroll
    for (int o = 0; o < CHUNK; o++) {
        int oc = g * CHUNK + o;
        float val = (acc[o] + bias[oc]) * mk;
        y[((size_t)b * COUT + oc) * T + t0 + tl] = val;
        s += val; s2 += val * val;
    }
    if constexpr (STATS) {
        rs[g * 64 + tl] = s; rs2[g * 64 + tl] = s2;
        __syncthreads();
        if (threadIdx.x < 64) {
            float ss = 0.f, ss2 = 0.f;
#pragma unroll
            for (int gg = 0; gg < NG; gg++) {
                ss += rs[gg * 64 + threadIdx.x];
                ss2 += rs2[gg * 64 + threadIdx.x];
            }
            float m = ss * (1.0f / COUT);
            float var = ss2 * (1.0f / COUT) - m * m;
            MM[(size_t)b * T + t0 + threadIdx.x] = m;
            IV[(size_t)b * T + t0 + threadIdx.x] = 1.0f / sqrtf(var + 1e-5f);
        }
    }
}

// ---------------- encoder fused sub-block (M=64), R17 structure -------------
// 512 thr / 8 waves.  Wave w owns conv1 n-tiles {w, 8+w} and conv2 n-tile w,
// for both m-tiles.  conv2 accumulates into the dead c0 (register reuse;
// peak acc = 64 f32).  MFMA issue round-robined across chains (per-chain
// order preserved -> bit-identical).  8 barriers.
template <int M>
__global__ __launch_bounds__(512, 4) void k_sub(
    const float* __restrict__ xin, float* __restrict__ xout,
    const float* __restrict__ MMi, const float* __restrict__ IVi,
    const float* __restrict__ lng, const float* __restrict__ lnb,
    const u16* __restrict__ B1H, const u16* __restrict__ B1L,
    const float* __restrict__ b1,
    const u16* __restrict__ B2H, const u16* __restrict__ B2L,
    const float* __restrict__ b2, const float* __restrict__ mask,
    float* __restrict__ MMo, float* __restrict__ IVo, int T) {
    constexpr int MT = M / 32;                 // m-tiles
    constexpr int SH = (M + 2) * 264 * 2;      // bytes per staged plane
    constexpr int CG = 512 / M;                // channel groups in stage/epi
    constexpr int CPT = 256 / CG;              // channels per thread
    __shared__ __align__(16) char smem[2 * SH + 4096];
    u16* LH = (u16*)smem;                      // [(M+2)][264]
    u16* LL = (u16*)(smem + SH);
    u16* GH = (u16*)smem;                      // overlay: [M][264]
    u16* GL = (u16*)(smem + SH);
    float* SOUT = (float*)smem;                // overlay: [M][260] f32
    float* rs  = (float*)(smem + 2 * SH);      // 512 f32
    float* rs2 = (float*)(smem + 2 * SH + 2048);

    const int tid = threadIdx.x;
    const int b = blockIdx.y, t0 = blockIdx.x * M;
    const size_t xoff = (size_t)b * 256 * T;
    const size_t bT = (size_t)b * T;

    // ---- stage: LN'd x, split hi/lo f16
    {
        int jj = tid & (M - 1);
        int cg = tid / M;
        int t = t0 - 2 + jj;
        bool ok = (t >= 0);
        float m = ok ? MMi[bT + t] : 0.f;
        float v = ok ? IVi[bT + t] : 0.f;
#pragma unroll
        for (int i = 0; i < CPT; i++) {
            int c = cg + i * CG;
            float xv = ok ? xin[xoff + (size_t)c * T + t] : 0.f;
            float ln = ok ? ((xv - m) * v * lng[c] + lnb[c]) : 0.f;
            u16 h, l; split_f16(ln, h, l);
            LH[jj * 264 + c] = h; LL[jj * 264 + c] = l;
        }
        int j2 = M + (tid >> 8);
        int c2 = tid & 255;
        int t2 = t0 + (M - 2) + (tid >> 8);
        float m2 = MMi[bT + t2], v2 = IVi[bT + t2];
        float x2 = xin[xoff + (size_t)c2 * T + t2];
        float ln2 = (x2 - m2) * v2 * lng[c2] + lnb[c2];
        u16 h2, l2; split_f16(ln2, h2, l2);
        LH[j2 * 264 + c2] = h2; LL[j2 * 264 + c2] = l2;
    }
    __syncthreads();                                   // (1)

    const int lane = tid & 63;
    const int w = tid >> 6;
    const int arow = lane & 31;
    const int acol = (lane >> 5) << 3;
    const int thalf = (lane >> 5) << 2;
    const int oc_l = w * 32 + (lane & 31);
    const u16* b1h0 = B1H + (size_t)w * 512 + (size_t)lane * 8;        // nt=w
    const u16* b1l0 = B1L + (size_t)w * 512 + (size_t)lane * 8;
    const u16* b1h1 = B1H + (size_t)(8 + w) * 512 + (size_t)lane * 8;  // nt=8+w
    const u16* b1l1 = B1L + (size_t)(8 + w) * 512 + (size_t)lane * 8;
    const u16* b2h = B2H + (size_t)w * 512 + (size_t)lane * 8;
    const u16* b2l = B2L + (size_t)w * 512 + (size_t)lane * 8;

    // ---- conv1: both output halves, all m-tiles, one pass.
    f32x16 c0[MT], c1[MT];
#pragma unroll
    for (int m = 0; m < MT; m++)
#pragma unroll
        for (int r = 0; r < 16; r++) { c0[m][r] = 0.f; c1[m][r] = 0.f; }
    __builtin_amdgcn_s_setprio(1);
#pragma unroll 2
    for (int kk = 0; kk < 48; kk++) {
        int k3 = kk >> 4, kb = kk & 15;
        f16x8 bh0 = *(const f16x8*)(b1h0 + (size_t)kk * 8192);
        f16x8 bl0 = *(const f16x8*)(b1l0 + (size_t)kk * 8192);
        f16x8 bh1 = *(const f16x8*)(b1h1 + (size_t)kk * 8192);
        f16x8 bl1 = *(const f16x8*)(b1l1 + (size_t)kk * 8192);
        f16x8 ah[MT], al[MT];
#pragma unroll
        for (int m = 0; m < MT; m++) {
            int ao = (m * 32 + arow + k3) * 264 + kb * 16 + acol;
            ah[m] = *(const f16x8*)&LH[ao];
            al[m] = *(const f16x8*)&LL[ao];
        }
#pragma unroll
        for (int m = 0; m < MT; m++) {
            c0[m] = __builtin_amdgcn_mfma_f32_32x32x16_f16(ah[m], bh0, c0[m], 0, 0, 0);
            c1[m] = __builtin_amdgcn_mfma_f32_32x32x16_f16(ah[m], bh1, c1[m], 0, 0, 0);
        }
#pragma unroll
        for (int m = 0; m < MT; m++) {
            c0[m] = __builtin_amdgcn_mfma_f32_32x32x16_f16(ah[m], bl0, c0[m], 0, 0, 0);
            c1[m] = __builtin_amdgcn_mfma_f32_32x32x16_f16(ah[m], bl1, c1[m], 0, 0, 0);
        }
#pragma unroll
        for (int m = 0; m < MT; m++) {
            c0[m] = __builtin_amdgcn_mfma_f32_32x32x16_f16(al[m], bh0, c0[m], 0, 0, 0);
            c1[m] = __builtin_amdgcn_mfma_f32_32x32x16_f16(al[m], bh1, c1[m], 0, 0, 0);
        }
    }
    __builtin_amdgcn_s_setprio(0);
    __syncthreads();                                   // (2) LH/LL dead

    // ---- pack p0 -> GH/GL (overlay on LH/LL region); c0 dies here
    {
        float bb = b1[oc_l];
#pragma unroll
        for (int m = 0; m < MT; m++)
#pragma unroll
            for (int r = 0; r < 16; r++) {
                int trow = m * 32 + thalf + ((r >> 2) << 3) + (r & 3);
                gelu_pack(c0[m][r], bb, GH, GL, trow * 264 + oc_l);
            }
    }
    __syncthreads();                                   // (3) G p0 visible

    // ---- conv2 p0: accumulate into c0 (register reuse; max acc = 64 f32)
#pragma unroll
    for (int m = 0; m < MT; m++)
#pragma unroll
        for (int r = 0; r < 16; r++) c0[m][r] = 0.f;
    __builtin_amdgcn_s_setprio(1);
#pragma unroll 2
    for (int i = 0; i < 16; i++) {
        f16x8 bh2 = *(const f16x8*)(b2h + (size_t)i * 4096);
        f16x8 bl2 = *(const f16x8*)(b2l + (size_t)i * 4096);
        f16x8 gh[MT], gl[MT];
#pragma unroll
        for (int m = 0; m < MT; m++) {
            int go = (m * 32 + arow) * 264 + i * 16 + acol;
            gh[m] = *(const f16x8*)&GH[go];
            gl[m] = *(const f16x8*)&GL[go];
        }
#pragma unroll
        for (int m = 0; m < MT; m++)
            c0[m] = __builtin_amdgcn_mfma_f32_32x32x16_f16(gh[m], bh2, c0[m], 0, 0, 0);
#pragma unroll
        for (int m = 0; m < MT; m++)
            c0[m] = __builtin_amdgcn_mfma_f32_32x32x16_f16(gh[m], bl2, c0[m], 0, 0, 0);
#pragma unroll
        for (int m = 0; m < MT; m++)
            c0[m] = __builtin_amdgcn_mfma_f32_32x32x16_f16(gl[m], bh2, c0[m], 0, 0, 0);
    }
    __builtin_amdgcn_s_setprio(0);
    __syncthreads();                                   // (4) G p0 reads done

    // ---- pack p1 -> GH/GL; c1 dies here
    {
        float bb = b1[256 + oc_l];
#pragma unroll
        for (int m = 0; m < MT; m++)
#pragma unroll
            for (int r = 0; r < 16; r++) {
                int trow = m * 32 + thalf + ((r >> 2) << 3) + (r & 3);
                gelu_pack(c1[m][r], bb, GH, GL, trow * 264 + oc_l);
            }
    }
    __syncthreads();                                   // (5) G p1 visible

    // ---- conv2 p1 (continue accumulating in c0)
    __builtin_amdgcn_s_setprio(1);
#pragma unroll 2
    for (int i = 0; i < 16; i++) {
        f16x8 bh2 = *(const f16x8*)(b2h + (size_t)(16 + i) * 4096);
        f16x8 bl2 = *(const f16x8*)(b2l + (size_t)(16 + i) * 4096);
        f16x8 gh[MT], gl[MT];
#pragma unroll
        for (int m = 0; m < MT; m++) {
            int go = (m * 32 + arow) * 264 + i * 16 + acol;
            gh[m] = *(const f16x8*)&GH[go];
            gl[m] = *(const f16x8*)&GL[go];
        }
#pragma unroll
        for (int m = 0; m < MT; m++)
            c0[m] = __builtin_amdgcn_mfma_f32_32x32x16_f16(gh[m], bh2, c0[m], 0, 0, 0);
#pragma unroll
        for (int m = 0; m < MT; m++)
            c0[m] = __builtin_amdgcn_mfma_f32_32x32x16_f16(gh[m], bl2, c0[m], 0, 0, 0);
#pragma unroll
        for (int m = 0; m < MT; m++)
            c0[m] = __builtin_amdgcn_mfma_f32_32x32x16_f16(gl[m], bh2, c0[m], 0, 0, 0);
    }
    __builtin_amdgcn_s_setprio(0);
    __syncthreads();                                   // (6) all G reads done

    // ---- SOUT (overlay on G region)
#pragma unroll
    for (int m = 0; m < MT; m++)
#pragma unroll
        for (int r = 0; r < 16; r++) {
            int trow = m * 32 + thalf + ((r >> 2) << 3) + (r & 3);
            SOUT[trow * 260 + oc_l] = c0[m][r];
        }
    __syncthreads();                                   // (7)
    {
        int t = tid & (M - 1), cg = tid / M;
        float mk = mask[bT + t0 + t];
        float s = 0.f, s2 = 0.f;
#pragma unroll
        for (int i = 0; i < CPT; i++) {
            int c = cg * CPT + i;
            size_t adr = xoff + (size_t)c * T + t0 + t;
            float val = (xin[adr] + SOUT[t * 260 + c] + b2[c]) * mk;
            xout[adr] = val;
            s += val; s2 += val * val;
        }
        rs[tid] = s; rs2[tid] = s2;
    }
    __syncthreads();                                   // (8)
    if (tid < M) {
        float ss = 0.f, ss2 = 0.f;
#pragma unroll
        for (int k = 0; k < CG; k++) {
            ss += rs[k * M + tid]; ss2 += rs2[k * M + tid];
        }
        float m = ss * (1.0f / 256.0f);
        float var = ss2 * (1.0f / 256.0f) - m * m;
        MMo[bT + t0 + tid] = m;
        IVo[bT + t0 + tid] = 1.0f / sqrtf(var + 1e-5f);
    }
}

// ---------------- postnet fused sub-block: M=32, 1024 thr / 16 waves --------
// grid = 256 = 1 block/CU -> LDS is free.  Full-K G [32][536]: single
// all-wave pack, conv2 split across all 16 waves; dual SOUT buffers.
__global__ __launch_bounds__(1024, 4) void k_sub16(
    const float* __restrict__ xin, float* __restrict__ xout,
    const float* __restrict__ MMi, const float* __restrict__ IVi,
    const float* __restrict__ lng, const float* __restrict__ lnb,
    const u16* __restrict__ B1H, const u16* __restrict__ B1L,
    const float* __restrict__ b1,
    const u16* __restrict__ B2H, const u16* __restrict__ B2L,
    const float* __restrict__ b2, const float* __restrict__ mask,
    float* __restrict__ MMo, float* __restrict__ IVo, int T) {
    __shared__ __align__(16) char smem[76800];
    u16* LH = (u16*)smem;                     // [34][264] u16 = 17952 B
    u16* LL = (u16*)(smem + 17952);           // 17952  (total 35904)
    u16* GH = (u16*)smem;                     // overlay [32][536] = 34304 B
    u16* GL = (u16*)(smem + 34304);           // 34304  (total 68608)
    float* SOUT  = (float*)smem;              // overlay [32][260] f32 = 33280
    float* SOUT2 = (float*)(smem + 34304);    // overlay on GL, 33280
    float* rs  = (float*)(smem + 68608);      // 1024 f32
    float* rs2 = (float*)(smem + 72704);      // 1024 f32

    const int tid = threadIdx.x;
    const int b = blockIdx.y, t0 = blockIdx.x * 32;
    const size_t xoff = (size_t)b * 256 * T;
    const size_t bT = (size_t)b * T;

    // ---- stage
    {
        int jj = tid & 31;
        int cg = tid >> 5;                    // 0..31
        int t = t0 - 2 + jj;
        bool ok = (t >= 0);
        float m = ok ? MMi[bT + t] : 0.f;
        float v = ok ? IVi[bT + t] : 0.f;
#pragma unroll
        for (int i = 0; i < 8; i++) {
            int c = cg + i * 32;
            float xv = ok ? xin[xoff + (size_t)c * T + t] : 0.f;
            float ln = ok ? ((xv - m) * v * lng[c] + lnb[c]) : 0.f;
            u16 h, l; split_f16(ln, h, l);
            LH[jj * 264 + c] = h; LL[jj * 264 + c] = l;
        }
        if (tid < 512) {
            int j2 = 32 + (tid >> 8);
            int c2 = tid & 255;
            int t2 = t0 + 30 + (tid >> 8);
            float ln2 = (xin[xoff + (size_t)c2 * T + t2] - MMi[bT + t2]) *
                        IVi[bT + t2] * lng[c2] + lnb[c2];
            u16 h2, l2; split_f16(ln2, h2, l2);
            LH[j2 * 264 + c2] = h2; LL[j2 * 264 + c2] = l2;
        }
    }
    __syncthreads();                                   // B1

    const int lane = tid & 63;
    const int w = tid >> 6;                            // 0..15
    const int arow = lane & 31;
    const int acol = (lane >> 5) << 3;
    const int thalf = (lane >> 5) << 2;
    const int oc_l = w * 32 + (lane & 31);             // 0..511
    const u16* b1h = B1H + (size_t)w * 512 + (size_t)lane * 8;   // nt = w
    const u16* b1l = B1L + (size_t)w * 512 + (size_t)lane * 8;

    // ---- conv1: one n-tile per wave (144 MFMA)
    f32x16 cc;
#pragma unroll
    for (int r = 0; r < 16; r++) cc[r] = 0.f;
    __builtin_amdgcn_s_setprio(1);
#pragma unroll 4
    for (int kk = 0; kk < 48; kk++) {
        int k3 = kk >> 4, kb = kk & 15;
        int ao = (arow + k3) * 264 + kb * 16 + acol;
        f16x8 ah = *(const f16x8*)&LH[ao];
        f16x8 al = *(const f16x8*)&LL[ao];
        f16x8 bh = *(const f16x8*)(b1h + (size_t)kk * 8192);
        f16x8 bl = *(const f16x8*)(b1l + (size_t)kk * 8192);
        cc = __builtin_amdgcn_mfma_f32_32x32x16_f16(ah, bh, cc, 0, 0, 0);
        cc = __builtin_amdgcn_mfma_f32_32x32x16_f16(ah, bl, cc, 0, 0, 0);
        cc = __builtin_amdgcn_mfma_f32_32x32x16_f16(al, bh, cc, 0, 0, 0);
    }
    __builtin_amdgcn_s_setprio(0);
    __syncthreads();                                   // B2: LH/LL dead

    // ---- pack: ALL 16 waves write their 32 oc columns of the full-K G
    {
        float bb = b1[oc_l];
#pragma unroll
        for (int r = 0; r < 16; r++) {
            int trow = thalf + ((r >> 2) << 3) + (r & 3);
            gelu_pack(cc[r], bb, GH, GL, trow * 536 + oc_l);
        }
    }
    __syncthreads();                                   // B3: G visible

    // ---- conv2: all 16 waves.  wave w: n-tile w&7, ic-half w>>3.
    const int nt2 = w & 7;
    const int ih = w >> 3;
    const u16* b2h = B2H + (size_t)nt2 * 512 + (size_t)lane * 8;
    const u16* b2l = B2L + (size_t)nt2 * 512 + (size_t)lane * 8;
#pragma unroll
    for (int r = 0; r < 16; r++) cc[r] = 0.f;
    __builtin_amdgcn_s_setprio(1);
#pragma unroll 4
    for (int i = 0; i < 16; i++) {
        int ii = ih * 16 + i;
        int go = arow * 536 + ii * 16 + acol;
        f16x8 gh = *(const f16x8*)&GH[go];
        f16x8 gl = *(const f16x8*)&GL[go];
        f16x8 bh2 = *(const f16x8*)(b2h + (size_t)ii * 4096);
        f16x8 bl2 = *(const f16x8*)(b2l + (size_t)ii * 4096);
        cc = __builtin_amdgcn_mfma_f32_32x32x16_f16(gh, bh2, cc, 0, 0, 0);
        cc = __builtin_amdgcn_mfma_f32_32x32x16_f16(gh, bl2, cc, 0, 0, 0);
        cc = __builtin_amdgcn_mfma_f32_32x32x16_f16(gl, bh2, cc, 0, 0, 0);
    }
    __builtin_amdgcn_s_setprio(0);
    __syncthreads();                                   // B4: all G reads done

    // ---- SOUT dual-buffer write (no RMW, no extra barrier)
    if (w < 8) {
#pragma unroll
        for (int r = 0; r < 16; r++) {
            int trow = thalf + ((r >> 2) << 3) + (r & 3);
            SOUT[trow * 260 + oc_l] = cc[r];
        }
    } else {
        int oc2 = nt2 * 32 + (lane & 31);
#pragma unroll
        for (int r = 0; r < 16; r++) {
            int trow = thalf + ((r >> 2) << 3) + (r & 3);
            SOUT2[trow * 260 + oc2] = cc[r];
        }
    }
    __syncthreads();                                   // B5
    {
        int t = tid & 31, cg = tid >> 5;               // cg 0..31
        float mk = mask[bT + t0 + t];
        float s = 0.f, s2 = 0.f;
#pragma unroll
        for (int i = 0; i < 8; i++) {
            int c = cg * 8 + i;
            size_t adr = xoff + (size_t)c * T + t0 + t;
            float val = (xin[adr] + (SOUT[t * 260 + c] + SOUT2[t * 260 + c]) +
                         b2[c]) * mk;
            xout[adr] = val;
            s += val; s2 += val * val;
        }
        rs[tid] = s; rs2[tid] = s2;
    }
    __syncthreads();                                   // B6
    if (tid < 32) {
        float ss = 0.f, ss2 = 0.f;
#pragma unroll
        for (int k = 0; k < 32; k++) {
            ss += rs[k * 32 + tid]; ss2 += rs2[k * 32 + tid];
        }
        float m = ss * (1.0f / 256.0f);
        float var = ss2 * (1.0f / 256.0f) - m * m;
        MMo[bT + t0 + tid] = m;
        IVo[bT + t0 + tid] = 1.0f / sqrtf(var + 1e-5f);
    }
}

// ---------------- final LN*mask + causal conv via MFMA (templated M) --------
template <int M>
__global__ __launch_bounds__(512, (M == 32 ? 8 : 4)) void k_lnc(
    const float* __restrict__ xin, float* __restrict__ xout,
    const float* __restrict__ MM, const float* __restrict__ IV,
    const float* __restrict__ lg, const float* __restrict__ lb,
    const u16* __restrict__ BH, const u16* __restrict__ BL,
    const float* __restrict__ bias, const float* __restrict__ mask, int T) {
    constexpr int MT = M / 32;
    constexpr int SH = (M + 2) * 264 * 2;
    constexpr int CG = 512 / M;
    constexpr int CPT = 256 / CG;
    __shared__ __align__(16) char smem[2 * SH];
    u16* LH = (u16*)smem;
    u16* LL = (u16*)(smem + SH);
    float* SOUT = (float*)smem;               // overlay

    const int tid = threadIdx.x;
    const int b = blockIdx.y, t0 = blockIdx.x * M;
    const size_t xoff = (size_t)b * 256 * T;
    const size_t bT = (size_t)b * T;

    {   // stage: (LN(x)*mask) hi/lo
        int jj = tid & (M - 1);
        int cg = tid / M;
        int t = t0 - 2 + jj;
        bool ok = (t >= 0);
        float m = ok ? MM[bT + t] : 0.f;
        float v = ok ? IV[bT + t] : 0.f;
        float mk = ok ? mask[bT + t] : 0.f;
#pragma unroll
        for (int i = 0; i < CPT; i++) {
            int c = cg + i * CG;
            float xv = ok ? xin[xoff + (size_t)c * T + t] : 0.f;
            float ln = ok ? ((xv - m) * v * lg[c] + lb[c]) * mk : 0.f;
            u16 h, l; split_f16(ln, h, l);
            LH[jj * 264 + c] = h; LL[jj * 264 + c] = l;
        }
        int j2 = M + (tid >> 8);
        int c2 = tid & 255;
        int t2 = t0 + (M - 2) + (tid >> 8);
        float ln2 = ((xin[xoff + (size_t)c2 * T + t2] - MM[bT + t2]) *
                     IV[bT + t2] * lg[c2] + lb[c2]) * mask[bT + t2];
        u16 h2, l2; split_f16(ln2, h2, l2);
        LH[j2 * 264 + c2] = h2; LL[j2 * 264 + c2] = l2;
    }
    __syncthreads();

    const int lane = tid & 63;
    const int w = tid >> 6;
    const int arow = lane & 31;
    const int acol = (lane >> 5) << 3;
    const int thalf = (lane >> 5) << 2;
    const u16* bph = BH + (size_t)w * 512 + (size_t)lane * 8;
    const u16* bpl = BL + (size_t)w * 512 + (size_t)lane * 8;

    f32x16 aH[MT], aM[MT];
#pragma unroll
    for (int m = 0; m < MT; m++)
#pragma unroll
        for (int r = 0; r < 16; r++) { aH[m][r] = 0.f; aM[m][r] = 0.f; }
    __builtin_amdgcn_s_setprio(1);
#pragma unroll 2
    for (int kk = 0; kk < 48; kk++) {
        int k3 = kk >> 4, kb = kk & 15;
        f16x8 bh = *(const f16x8*)(bph + (size_t)kk * 4096);
        f16x8 bl = *(const f16x8*)(bpl + (size_t)kk * 4096);
        f16x8 ah[MT], al[MT];
#pragma unroll
        for (int m = 0; m < MT; m++) {
            int ao = (m * 32 + arow + k3) * 264 + kb * 16 + acol;
            ah[m] = *(const f16x8*)&LH[ao];
            al[m] = *(const f16x8*)&LL[ao];
        }
#pragma unroll
        for (int m = 0; m < MT; m++)
            aH[m] = __builtin_amdgcn_mfma_f32_32x32x16_f16(ah[m], bh, aH[m], 0, 0, 0);
#pragma unroll
        for (int m = 0; m < MT; m++)
            aM[m] = __builtin_amdgcn_mfma_f32_32x32x16_f16(ah[m], bl, aM[m], 0, 0, 0);
#pragma unroll
        for (int m = 0; m < MT; m++)
            aM[m] = __builtin_amdgcn_mfma_f32_32x32x16_f16(al[m], bh, aM[m], 0, 0, 0);
    }
    __builtin_amdgcn_s_setprio(0);
    __syncthreads();  // all LH/LL reads done before SOUT overlay
    {
        int oc = w * 32 + (lane & 31);
#pragma unroll
        for (int m = 0; m < MT; m++)
#pragma unroll
            for (int r = 0; r < 16; r++) {
                int trow = m * 32 + thalf + ((r >> 2) << 3) + (r & 3);
                SOUT[trow * 260 + oc] = aH[m][r] + aM[m][r];
            }
    }
    __syncthreads();
    {
        int t = tid & (M - 1), cg = tid / M;
        float mk = mask[bT + t0 + t];
#pragma unroll
        for (int i = 0; i < CPT; i++) {
            int c = cg * CPT + i;
            xout[xoff + (size_t)c * T + t0 + t] =
                (SOUT[t * 260 + c] + bias[c]) * mk;
        }
    }
}

// ---------------- group-by-segments (scatter mean) --------------------------
__global__ __launch_bounds__(256) void k_counts(const int* __restrict__ m2p,
                                                int* __restrict__ cnt) {
    __shared__ int c[512];
    int b = blockIdx.x;
    for (int i = threadIdx.x; i < 512; i += 256) c[i] = 0;
    __syncthreads();
    for (int t = threadIdx.x; t < 2048; t += 256) {
        int p = m2p[b * 2048 + t];
        if (p >= 1 && p <= 512) atomicAdd(&c[p - 1], 1);
    }
    __syncthreads();
    for (int i = threadIdx.x; i < 512; i += 256) cnt[b * 512 + i] = c[i];
}

__global__ __launch_bounds__(256) void k_scatter(const float* __restrict__ h,
                                                 const int* __restrict__ m2p,
                                                 float* __restrict__ g) {
    extern __shared__ float sm[];
    float* HT = sm;
    int* ph = (int*)(sm + 256 * 65);
    int b = blockIdx.y, t0 = blockIdx.x * 64;
    if (threadIdx.x < 64) ph[threadIdx.x] = m2p[b * 2048 + t0 + threadIdx.x];
    for (int i = threadIdx.x; i < 256 * 64; i += 256) {
        int c = i >> 6, j = i & 63;
        HT[c * 65 + j] = h[((size_t)b * 256 + c) * 2048 + t0 + j];
    }
    __syncthreads();
    int c = threadIdx.x;
    float run = 0.f;
    int cur = ph[0];
    for (int j = 0; j < 64; j++) {
        int p = ph[j];
        if (p != cur) {
            if (cur >= 1 && cur <= 512)
                atomicAdd(&g[((size_t)b * 256 + c) * 512 + cur - 1], run);
            run = 0.f;
            cur = p;
        }
        run += HT[c * 65 + j];
    }
    if (cur >= 1 && cur <= 512)
        atomicAdd(&g[((size_t)b * 256 + c) * 512 + cur - 1], run);
}

__global__ __launch_bounds__(512) void k_postprep(float* __restrict__ g,
                                                  const int* __restrict__ cnt,
                                                  float* __restrict__ MM,
                                                  float* __restrict__ IV) {
    int b = blockIdx.x, l = threadIdx.x;
    int c1 = cnt[b * 512 + l];
    if (c1 < 1) c1 = 1;
    float rc = 1.0f / (float)c1;
    float s = 0.f, s2 = 0.f;
    for (int c = 0; c < 256; c++) {
        size_t idx = ((size_t)b * 256 + c) * 512 + l;
        float v = g[idx] * rc;
        g[idx] = v;
        s += v; s2 += v * v;
    }
    float m = s * (1.0f / 256.0f);
    float var = s2 * (1.0f / 256.0f) - m * m;
    MM[(size_t)b * 512 + l] = m;
    IV[(size_t)b * 512 + l] = 1.0f / sqrtf(var + 1e-5f);
}

// ---------------- VQ (lane-pair K-split) ------------------------------------
__global__ __launch_bounds__(256) void k_vq(const float* __restrict__ z,
                                            const float* __restrict__ cb,
                                            int* __restrict__ idxout,
                                            float* __restrict__ out,
                                            float* __restrict__ lossacc) {
    int n2 = blockIdx.x * 256 + threadIdx.x;   // 16384 total (grid 64)
    int n = n2 >> 1;                           // (b,l) work item
    int half = n2 & 1;                         // codebook half
    int b = n >> 9, l = n & 511;
    float zr[64];
#pragma unroll
    for (int c = 0; c < 64; c++) zr[c] = z[((size_t)b * 64 + c) * 512 + l];
    float best = 3.4e38f;
    int bi = 0;
    int k0 = half * 64;
    for (int k = k0; k < k0 + 64; k++) {
        const float* cr = cb + k * 64;
        float d = 0.f;
#pragma unroll
        for (int c = 0; c < 64; c++) {
            float t = zr[c] - cr[c];
            d = fmaf(t, t, d);
        }
        if (d < best) { best = d; bi = k; }
    }
    // combine across the lane pair (first-min semantics: lower k wins ties)
    float bestO = __shfl_xor(best, 1);
    int biO = __shfl_xor(bi, 1);
    if (bestO < best || (bestO == best && biO < bi)) { best = bestO; bi = biO; }
    if (half == 0) {
        idxout[n] = bi;
        out[OUT_IDX_OFF + n] = (float)bi;
        atomicAdd(lossacc, best);
    }
}

__global__ void k_loss(const float* __restrict__ acc, float* __restrict__ out) {
    if (threadIdx.x == 0 && blockIdx.x == 0)
        out[OUT_LOSS_OFF] = 0.25f * acc[0] * (1.0f / 524288.0f);
}

// ---------------- proj_out --------------------------------------------------
__global__ __launch_bounds__(256) void k_projout(const float* __restrict__ cb,
                                                 const int* __restrict__ idx,
                                                 const float* __restrict__ wt,
                                                 const float* __restrict__ bias,
                                                 float* __restrict__ out) {
    __shared__ float Q[64 * 64];
    __shared__ int ids[64];
    int b = blockIdx.y, l0 = blockIdx.x * 64;
    if (threadIdx.x < 64) ids[threadIdx.x] = idx[b * 512 + l0 + threadIdx.x];
    __syncthreads();
    for (int i = threadIdx.x; i < 4096; i += 256) {
        int c = i >> 6, l = i & 63;
        Q[c * 64 + l] = cb[ids[l] * 64 + c];
    }
    __syncthreads();
    int tl = threadIdx.x & 63;
    int g = __builtin_amdgcn_readfirstlane((int)(threadIdx.x >> 6));
    float acc[64];
#pragma unroll
    for (int o = 0; o < 64; o++) acc[o] = 0.f;
    for (int i = 0; i < 64; i++) {
        float xv = Q[i * 64 + tl];
        const float* wr = wt + i * 256 + g * 64;
#pragma unroll
        for (int o = 0; o < 64; o++) acc[o] = fmaf(wr[o], xv, acc[o]);
    }
#pragma unroll
    for (int o = 0; o < 64; o++) {
        int oc = g * 64 + o;
        out[(size_t)b * 131072 + (size_t)oc * 512 + l0 + tl] = acc[o] + bias[oc];
    }
}

// ---------------------------------------------------------------------------
extern "C" void kernel_launch(void* const* d_in, const int* in_sizes, int n_in,
                              void* d_out, int out_size, void* d_ws, size_t ws_size,
                              hipStream_t stream) {
    (void)in_sizes; (void)n_in; (void)out_size; (void)ws_size;
    const float* x          = (const float*)d_in[0];
    const float* in_np      = (const float*)d_in[1];
    const int*   mel2ph     = (const int*)d_in[2];
    const float* ph_np      = (const float*)d_in[3];
    const float* conv_in_w  = (const float*)d_in[4];
    const float* conv_in_b  = (const float*)d_in[5];
    const float* e_ln_g = (const float*)d_in[6];
    const float* e_ln_b = (const float*)d_in[7];
    const float* e_w1   = (const float*)d_in[8];
    const float* e_b1   = (const float*)d_in[9];
    const float* e_w2   = (const float*)d_in[10];
    const float* e_b2   = (const float*)d_in[11];
    const float* e_lg   = (const float*)d_in[12];
    const float* e_lb   = (const float*)d_in[13];
    const float* e_pw   = (const float*)d_in[14];
    const float* e_pb   = (const float*)d_in[15];
    const float* p_ln_g = (const float*)d_in[16];
    const float* p_ln_b = (const float*)d_in[17];
    const float* p_w1   = (const float*)d_in[18];
    const float* p_b1   = (const float*)d_in[19];
    const float* p_w2   = (const float*)d_in[20];
    const float* p_b2   = (const float*)d_in[21];
    const float* p_lg   = (const float*)d_in[22];
    const float* p_lb   = (const float*)d_in[23];
    const float* p_pw   = (const float*)d_in[24];
    const float* p_pb   = (const float*)d_in[25];
    const float* proj_in_w  = (const float*)d_in[26];
    const float* proj_in_b  = (const float*)d_in[27];
    const float* proj_out_w = (const float*)d_in[28];
    const float* proj_out_b = (const float*)d_in[29];
    const float* codebook   = (const float*)d_in[30];
    float* out = (float*)d_out;

    float* ws = (float*)d_ws;
    float* A      = ws;                        // 8388608
    float* Bb     = A + 8388608;               // 8388608
    float* CINT   = Bb + 8388608;              // 20480
    float* PINT   = CINT + 20480;              // 16384
    float* POUTT  = PINT + 16384;              // 16384
    float* Z      = POUTT + 16384;             // 524288
    float* MM0    = Z + 524288;                // 32768
    float* IV0    = MM0 + 32768;               // 32768
    float* MM1    = IV0 + 32768;               // 32768
    float* IV1    = MM1 + 32768;               // 32768
    int*   CNT    = (int*)(IV1 + 32768);       // 8192
    int*   IDX    = CNT + 8192;                // 8192
    float* LOSS   = (float*)(IDX + 8192);      // 64 (aligned pad)
    u16*   BH1E   = (u16*)(LOSS + 64);         // 3932160 each
    u16*   BL1E   = BH1E + 3932160;
    u16*   BH1P   = BL1E + 3932160;
    u16*   BL1P   = BH1P + 3932160;
    u16*   BH2E   = BL1P + 3932160;            // 1310720 each
    u16*   BL2E   = BH2E + 1310720;
    u16*   BH2P   = BL2E + 1310720;
    u16*   BL2P   = BH2P + 1310720;
    u16*   PH_E   = BL2P + 1310720;            // 196608 each
    u16*   PL_E   = PH_E + 196608;
    u16*   PH_P   = PL_E + 196608;
    u16*   PL_P   = PH_P + 196608;

    // weight prep (ws re-poisoned every call -> recompute); fused launches
    k_t_w1mf2<<<dim3(8192), dim3(256), 0, stream>>>(e_w1, p_w1,
                                                    BH1E, BL1E, BH1P, BL1P);
    k_t_w2mf2<<<dim3(4096), dim3(256), 0, stream>>>(e_w2, p_w2,
                                                    BH2E, BL2E, BH2P, BL2P);
    k_t_wpmf2<<<dim3(1536), dim3(256), 0, stream>>>(e_pw, p_pw,
                                                    PH_E, PL_E, PH_P, PL_P);
    k_t_mat3<<<dim3(208), dim3(256), 0, stream>>>(conv_in_w, proj_in_w,
                                                  proj_out_w, CINT, PINT, POUTT);

    const size_t sm_scat = 256 * 65 * sizeof(float) + 64 * sizeof(int);

    // ---- conv_in + mask -> A (+ LN stats for encoder layer 0)
    k_pw<80, 256, 64, true><<<dim3(32, 16), dim3(256), 80 * 64 * 4, stream>>>(
        x, CINT, conv_in_b, in_np, A, MM0, IV0, 2048);

    // ---- encoder: 10 fused sub-blocks (M=64), ping-pong A<->B and MM0/1
    float* cur = A;
    float* nxt = Bb;
    for (int s = 0; s < 10; s++) {
        float* mi = (s & 1) ? MM1 : MM0;
        float* vi = (s & 1) ? IV1 : IV0;
        float* mo = (s & 1) ? MM0 : MM1;
        float* vo = (s & 1) ? IV0 : IV1;
        k_sub<64><<<dim3(32, 16), dim3(512), 0, stream>>>(
            cur, nxt, mi, vi, e_ln_g + s * 256, e_ln_b + s * 256,
            BH1E + (size_t)s * 393216, BL1E + (size_t)s * 393216, e_b1 + s * 512,
            BH2E + (size_t)s * 131072, BL2E + (size_t)s * 131072, e_b2 + s * 256,
            in_np, mo, vo, 2048);
        float* t = cur; cur = nxt; nxt = t;
    }
    // final stats in MM0/IV0 (s=9 odd -> wrote MM0)
    k_lnc<64><<<dim3(32, 16), dim3(512), 0, stream>>>(
        cur, nxt, MM0, IV0, e_lg, e_lb, PH_E, PL_E, e_pb, in_np, 2048);

    // ---- group-by-segs: B (T=2048) -> A (compact [16,256,512])
    hipMemsetAsync(A, 0, (size_t)2097152 * 4, stream);
    hipMemsetAsync(LOSS, 0, 4, stream);
    k_counts<<<dim3(16), dim3(256), 0, stream>>>(mel2ph, CNT);
    k_scatter<<<dim3(32, 16), dim3(256), sm_scat, stream>>>(Bb, mel2ph, A);
    k_postprep<<<dim3(16), dim3(512), 0, stream>>>(A, CNT, MM0, IV0);

    // ---- postnet: 10 fused sub-blocks on T=512 (M=32, 16 waves)
    cur = A; nxt = Bb;
    for (int s = 0; s < 10; s++) {
        float* mi = (s & 1) ? MM1 : MM0;
        float* vi = (s & 1) ? IV1 : IV0;
        float* mo = (s & 1) ? MM0 : MM1;
        float* vo = (s & 1) ? IV0 : IV1;
        k_sub16<<<dim3(16, 16), dim3(1024), 0, stream>>>(
            cur, nxt, mi, vi, p_ln_g + s * 256, p_ln_b + s * 256,
            BH1P + (size_t)s * 393216, BL1P + (size_t)s * 393216, p_b1 + s * 512,
            BH2P + (size_t)s * 131072, BL2P + (size_t)s * 131072, p_b2 + s * 256,
            ph_np, mo, vo, 512);
        float* t = cur; cur = nxt; nxt = t;
    }
    k_lnc<32><<<dim3(16, 16), dim3(512), 0, stream>>>(
        cur, nxt, MM0, IV0, p_lg, p_lb, PH_P, PL_P, p_pb, ph_np, 512);

    // ---- proj_in: B -> Z [16,64,512]
    k_pw<256, 64, 16, false><<<dim3(8, 16), dim3(256), 256 * 64 * 4, stream>>>(
        Bb, PINT, proj_in_b, nullptr, Z, nullptr, nullptr, 512);

    // ---- VQ + loss + proj_out
    k_vq<<<dim3(64), dim3(256), 0, stream>>>(Z, codebook, IDX, out, LOSS);
    k_loss<<<dim3(1), dim3(64), 0, stream>>>(LOSS, out);
    k_projout<<<dim3(8, 16), dim3(256), 0, stream>>>(codebook, IDX, POUTT,
                                                     proj_out_b, out);
}